// Round 1
// baseline (3956.240 us; speedup 1.0000x reference)
//
#include <hip/hip_runtime.h>
#include <hip/hip_bf16.h>
#include <math.h>

#define DEVI __device__ __forceinline__

namespace {
constexpr int kL   = 1024;
constexpr int kDM  = 512;
constexpr int kDS  = 16;
constexpr int kDFF = 2048;
constexpr int kR   = 32;
constexpr int kDI  = 512;
constexpr int kB   = 16;
constexpr int kM   = kB * kL;     // 16384 rows
constexpr int kNC  = 32;          // scan chunks
constexpr int kCH  = kL / kNC;    // 32 steps per chunk
}

DEVI float silu_f(float x)     { return x / (1.f + __expf(-x)); }
DEVI float softplus_f(float x) { return fmaxf(x, 0.f) + log1pf(__expf(-fabsf(x))); }
DEVI float gelu_f(float x)     { return 0.5f * x * (1.f + erff(x * 0.70710678118654752f)); }

// ---------------------------------------------------------------------------
// Tiled f32 GEMM:  C[m,n] = epi( sum_k A[m*lda+k] * W[n*Kd+k] )
// EPI: 0 plain store, 1 bias+softplus, 2 accumulate (C+=), 3 bias+gelu,
//      4 bias + add[m,n] store.
// Block tile: 128 x BN (BN = 16*TN), 256 threads, micro-tile 8 x TN, BK=16.
// ---------------------------------------------------------------------------
template <int EPI, int BN, int TN>
__global__ __launch_bounds__(256) void gemm_f32(
    const float* __restrict__ A, int lda,
    const float* __restrict__ W,
    float* __restrict__ C, int ldc,
    const float* __restrict__ bias, const float* __restrict__ add,
    int Kd)
{
    __shared__ float As[16][132];
    __shared__ float Ws[16][BN + 4];
    const int tid  = threadIdx.x;
    const int tx   = tid & 15;
    const int ty   = tid >> 4;
    const int row0 = blockIdx.y * 128;
    const int col0 = blockIdx.x * BN;
    const int lr   = tid >> 2;         // 0..63
    const int lc   = (tid & 3) << 2;   // 0,4,8,12

    float acc[8][TN];
#pragma unroll
    for (int i = 0; i < 8; ++i)
#pragma unroll
        for (int j = 0; j < TN; ++j) acc[i][j] = 0.f;

    const float* Arow0 = A + (size_t)(row0 + lr) * lda + lc;
    const float* Arow1 = A + (size_t)(row0 + lr + 64) * lda + lc;
    const float* Wrow0 = W + (size_t)(col0 + lr) * Kd + lc;
    const float* Wrow1 = W + (size_t)(col0 + lr + 64) * Kd + lc;  // only if BN==128

    for (int k0 = 0; k0 < Kd; k0 += 16) {
        float4 a0 = *(const float4*)(Arow0 + k0);
        float4 a1 = *(const float4*)(Arow1 + k0);
        float4 w0 = *(const float4*)(Wrow0 + k0);
        float4 w1;
        if (BN == 128) w1 = *(const float4*)(Wrow1 + k0);
        __syncthreads();
        As[lc + 0][lr]      = a0.x; As[lc + 1][lr]      = a0.y;
        As[lc + 2][lr]      = a0.z; As[lc + 3][lr]      = a0.w;
        As[lc + 0][lr + 64] = a1.x; As[lc + 1][lr + 64] = a1.y;
        As[lc + 2][lr + 64] = a1.z; As[lc + 3][lr + 64] = a1.w;
        Ws[lc + 0][lr]      = w0.x; Ws[lc + 1][lr]      = w0.y;
        Ws[lc + 2][lr]      = w0.z; Ws[lc + 3][lr]      = w0.w;
        if (BN == 128) {
            Ws[lc + 0][lr + 64] = w1.x; Ws[lc + 1][lr + 64] = w1.y;
            Ws[lc + 2][lr + 64] = w1.z; Ws[lc + 3][lr + 64] = w1.w;
        }
        __syncthreads();
#pragma unroll
        for (int kk = 0; kk < 16; ++kk) {
            float4 av0 = *(const float4*)&As[kk][ty * 8];
            float4 av1 = *(const float4*)&As[kk][ty * 8 + 4];
            float am[8] = {av0.x, av0.y, av0.z, av0.w, av1.x, av1.y, av1.z, av1.w};
            float bn[TN];
            float4 bv0 = *(const float4*)&Ws[kk][tx * TN];
            bn[0] = bv0.x; bn[1] = bv0.y; bn[2] = bv0.z; bn[3] = bv0.w;
            if (TN == 8) {
                float4 bv1 = *(const float4*)&Ws[kk][tx * TN + 4];
                bn[4] = bv1.x; bn[5] = bv1.y; bn[6] = bv1.z; bn[7] = bv1.w;
            }
#pragma unroll
            for (int i = 0; i < 8; ++i)
#pragma unroll
                for (int j = 0; j < TN; ++j)
                    acc[i][j] = fmaf(am[i], bn[j], acc[i][j]);
        }
    }

#pragma unroll
    for (int i = 0; i < 8; ++i) {
        int r = row0 + ty * 8 + i;
#pragma unroll
        for (int j = 0; j < TN; ++j) {
            int cn = col0 + tx * TN + j;
            size_t idx = (size_t)r * ldc + cn;
            float v = acc[i][j];
            if constexpr (EPI == 0) {
                C[idx] = v;
            } else if constexpr (EPI == 1) {
                C[idx] = softplus_f(v + bias[cn]);
            } else if constexpr (EPI == 2) {
                C[idx] += v;
            } else if constexpr (EPI == 3) {
                C[idx] = gelu_f(v + bias[cn]);
            } else {
                C[idx] = v + bias[cn] + add[idx];
            }
        }
    }
}

// ---------------------------------------------------------------------------
// Depthwise causal/anti-causal conv (K=4) + bias + silu.
// xz: (kM, 1024), cols 0..511 hold the conv input; out xc: (kM, 512)
// ---------------------------------------------------------------------------
__global__ __launch_bounds__(256) void conv_silu_k(
    const float* __restrict__ xz, float* __restrict__ xc,
    const float* __restrict__ w, const float* __restrict__ bias, int dir)
{
    int idx = blockIdx.x * 256 + threadIdx.x;
    if (idx >= kM * kDI) return;
    int d   = idx & (kDI - 1);
    int row = idx >> 9;
    int t   = row & (kL - 1);
    int b   = row >> 10;
    float acc = bias[d];
#pragma unroll
    for (int k = 0; k < 4; ++k) {
        int tt = dir ? (t + 3 - k) : (t - 3 + k);
        if (tt >= 0 && tt < kL)
            acc = fmaf(w[d * 4 + k], xz[(size_t)(b * kL + tt) * 1024 + d], acc);
    }
    xc[idx] = silu_f(acc);
}

// ---------------------------------------------------------------------------
// Chunked selective scan.
// Layouts: dt/xc/y: (kM, kDI). dbl: (kM, 64) [dt0|B|C]. S/h0: [b][c][s][d].
// ---------------------------------------------------------------------------
__global__ __launch_bounds__(256) void scan_chunk(
    const float* __restrict__ dtb, const float* __restrict__ xcb,
    const float* __restrict__ dbl, const float* __restrict__ A_log,
    float* __restrict__ S, float* __restrict__ sdt, int dir)
{
    int blk  = blockIdx.x;
    int dblk = blk & 1;
    int c    = (blk >> 1) & (kNC - 1);
    int b    = blk >> 6;                  // /(2*kNC)
    int d    = dblk * 256 + threadIdx.x;

    const float* al = A_log + d * kDS;
    float A[16];
#pragma unroll
    for (int s = 0; s < 16; ++s) A[s] = -__expf(al[s]);

    float h[16];
#pragma unroll
    for (int s = 0; s < 16; ++s) h[s] = 0.f;
    float sum = 0.f;

    for (int i = 0; i < kCH; ++i) {
        int p   = c * kCH + i;
        int t   = dir ? (kL - 1 - p) : p;
        int row = b * kL + t;
        float dt = dtb[(size_t)row * kDI + d];
        float xv = xcb[(size_t)row * kDI + d];
        sum += dt;
        float dx = dt * xv;
        const float4* bp = (const float4*)(dbl + (size_t)row * 64 + kR);
        float4 b0 = bp[0], b1 = bp[1], b2 = bp[2], b3 = bp[3];
        float Bv[16] = {b0.x, b0.y, b0.z, b0.w, b1.x, b1.y, b1.z, b1.w,
                        b2.x, b2.y, b2.z, b2.w, b3.x, b3.y, b3.z, b3.w};
#pragma unroll
        for (int s = 0; s < 16; ++s) {
            float q = __expf(dt * A[s]);
            h[s] = fmaf(q, h[s], dx * Bv[s]);
        }
    }
    size_t base = (size_t)(b * kNC + c) * kDS * kDI + d;
#pragma unroll
    for (int s = 0; s < 16; ++s) S[base + s * kDI] = h[s];
    sdt[(size_t)(b * kNC + c) * kDI + d] = sum;
}

__global__ __launch_bounds__(256) void scan_carry(
    const float* __restrict__ S, const float* __restrict__ sdt,
    const float* __restrict__ A_log, float* __restrict__ h0)
{
    int g = blockIdx.x * 256 + threadIdx.x;  // 0..8191
    int b = g >> 9;
    int d = g & (kDI - 1);
    const float* al = A_log + d * kDS;
    float A[16];
#pragma unroll
    for (int s = 0; s < 16; ++s) A[s] = -__expf(al[s]);
    float h[16];
#pragma unroll
    for (int s = 0; s < 16; ++s) h[s] = 0.f;

    for (int c = 0; c < kNC; ++c) {
        size_t base = (size_t)(b * kNC + c) * kDS * kDI + d;
        float sd = sdt[(size_t)(b * kNC + c) * kDI + d];
#pragma unroll
        for (int s = 0; s < 16; ++s) {
            h0[base + s * kDI] = h[s];
            float P = __expf(sd * A[s]);
            h[s] = fmaf(P, h[s], S[base + s * kDI]);
        }
    }
}

__global__ __launch_bounds__(256) void scan_emit(
    const float* __restrict__ dtb, const float* __restrict__ xcb,
    const float* __restrict__ dbl, const float* __restrict__ A_log,
    const float* __restrict__ h0v, const float* __restrict__ Dp,
    const float* __restrict__ xz, float* __restrict__ yb, int dir)
{
    int blk  = blockIdx.x;
    int dblk = blk & 1;
    int c    = (blk >> 1) & (kNC - 1);
    int b    = blk >> 6;
    int d    = dblk * 256 + threadIdx.x;

    const float* al = A_log + d * kDS;
    float A[16];
#pragma unroll
    for (int s = 0; s < 16; ++s) A[s] = -__expf(al[s]);
    float Dd = Dp[d];

    size_t hbase = (size_t)(b * kNC + c) * kDS * kDI + d;
    float h[16];
#pragma unroll
    for (int s = 0; s < 16; ++s) h[s] = h0v[hbase + s * kDI];

    for (int i = 0; i < kCH; ++i) {
        int p   = c * kCH + i;
        int t   = dir ? (kL - 1 - p) : p;
        int row = b * kL + t;
        float dt = dtb[(size_t)row * kDI + d];
        float xv = xcb[(size_t)row * kDI + d];
        float dx = dt * xv;
        const float4* bp = (const float4*)(dbl + (size_t)row * 64 + kR);
        float4 b0 = bp[0], b1 = bp[1], b2 = bp[2], b3 = bp[3];
        const float4* cp = (const float4*)(dbl + (size_t)row * 64 + kR + kDS);
        float4 c0 = cp[0], c1 = cp[1], c2 = cp[2], c3 = cp[3];
        float Bv[16] = {b0.x, b0.y, b0.z, b0.w, b1.x, b1.y, b1.z, b1.w,
                        b2.x, b2.y, b2.z, b2.w, b3.x, b3.y, b3.z, b3.w};
        float Cv[16] = {c0.x, c0.y, c0.z, c0.w, c1.x, c1.y, c1.z, c1.w,
                        c2.x, c2.y, c2.z, c2.w, c3.x, c3.y, c3.z, c3.w};
        float y = 0.f;
#pragma unroll
        for (int s = 0; s < 16; ++s) {
            float q = __expf(dt * A[s]);
            h[s] = fmaf(q, h[s], dx * Bv[s]);
            y = fmaf(h[s], Cv[s], y);
        }
        y += xv * Dd;
        float z = xz[(size_t)row * 1024 + 512 + d];
        yb[(size_t)row * kDI + d] = y * silu_f(z);
    }
}

// ---------------------------------------------------------------------------
// LayerNorm over rows of 512. One block (128 threads) per row. Safe in-place.
// ---------------------------------------------------------------------------
__global__ __launch_bounds__(128) void ln_k(
    const float* __restrict__ in, const float* __restrict__ g,
    const float* __restrict__ bb, float* __restrict__ out)
{
    int row = blockIdx.x;
    int tid = threadIdx.x;
    float4 v = *(const float4*)&in[(size_t)row * kDM + tid * 4];
    float s1 = v.x + v.y + v.z + v.w;
    float s2 = v.x * v.x + v.y * v.y + v.z * v.z + v.w * v.w;
#pragma unroll
    for (int off = 32; off >= 1; off >>= 1) {
        s1 += __shfl_xor(s1, off);
        s2 += __shfl_xor(s2, off);
    }
    __shared__ float red[4];
    if ((tid & 63) == 0) { red[(tid >> 6) * 2] = s1; red[(tid >> 6) * 2 + 1] = s2; }
    __syncthreads();
    s1 = red[0] + red[2];
    s2 = red[1] + red[3];
    float mu  = s1 * (1.f / kDM);
    float var = s2 * (1.f / kDM) - mu * mu;
    float rs  = rsqrtf(var + 1e-5f);
    int cn = tid * 4;
    float4 gv = *(const float4*)&g[cn];
    float4 bv = *(const float4*)&bb[cn];
    float4 o;
    o.x = (v.x - mu) * rs * gv.x + bv.x;
    o.y = (v.y - mu) * rs * gv.y + bv.y;
    o.z = (v.z - mu) * rs * gv.z + bv.z;
    o.w = (v.w - mu) * rs * gv.w + bv.w;
    *(float4*)&out[(size_t)row * kDM + cn] = o;
}

// ---------------------------------------------------------------------------
extern "C" void kernel_launch(void* const* d_in, const int* in_sizes, int n_in,
                              void* d_out, int out_size, void* d_ws, size_t ws_size,
                              hipStream_t stream)
{
    const float* x_in    = (const float*)d_in[0];
    const float* in_w    = (const float*)d_in[1];
    const float* conv_w  = (const float*)d_in[2];
    const float* conv_b  = (const float*)d_in[3];
    const float* xproj_w = (const float*)d_in[4];
    const float* dt_w    = (const float*)d_in[5];
    const float* dt_b    = (const float*)d_in[6];
    const float* A_log   = (const float*)d_in[7];
    const float* Dp      = (const float*)d_in[8];
    const float* out_w   = (const float*)d_in[9];
    const float* ff_w1   = (const float*)d_in[10];
    const float* ff_b1   = (const float*)d_in[11];
    const float* ff_w2   = (const float*)d_in[12];
    const float* ff_b2   = (const float*)d_in[13];
    const float* ln1_g   = (const float*)d_in[14];
    const float* ln1_b   = (const float*)d_in[15];
    const float* ln2_g   = (const float*)d_in[16];
    const float* ln2_b   = (const float*)d_in[17];
    const float* lnf_g   = (const float*)d_in[18];
    const float* lnf_b   = (const float*)d_in[19];

    float* ws = (float*)d_ws;
    // mamba-phase buffers
    float* xz  = ws;                   // 16,777,216  (kM x 1024)
    float* xcb = ws + 16777216;        //  8,388,608  (kM x 512)
    float* dtb = ws + 25165824;        //  8,388,608
    float* dbl = ws + 33554432;        //  1,048,576  (kM x 64)
    float* yb  = ws + 34603008;        //  8,388,608
    float* Sb  = ws + 42991616;        //  4,194,304
    float* h0b = ws + 47185920;        //  4,194,304
    float* sdt = ws + 51380224;        //    262,144
    // ffn-phase aliases (mamba buffers dead by then)
    float* xn  = ws + 42991616;        //  8,388,608 over Sb/h0b/sdt
    float* Hb  = ws;                   // 33,554,432 over xz/xcb/dtb
    float* t2  = ws + 33554432;        //  8,388,608 over dbl/yb

    float* xcur = (float*)d_out;

    hipMemcpyAsync(xcur, x_in, (size_t)kM * kDM * sizeof(float),
                   hipMemcpyDeviceToDevice, stream);

    dim3 thr(256);
    for (int e = 0; e < 2; ++e) {
        for (int dir = 0; dir < 2; ++dir) {
            int ed = e * 2 + dir;
            // in-proj: (kM x 512) @ (1024 x 512)^T -> xz (kM x 1024)
            gemm_f32<0, 128, 8><<<dim3(1024 / 128, kM / 128), thr, 0, stream>>>(
                xcur, 512, in_w + (size_t)ed * 1024 * 512, xz, 1024,
                nullptr, nullptr, 512);
            conv_silu_k<<<dim3(kM * kDI / 256), thr, 0, stream>>>(
                xz, xcb, conv_w + (size_t)ed * kDI * 4, conv_b + (size_t)ed * kDI, dir);
            // x-proj: (kM x 512) @ (64 x 512)^T -> dbl (kM x 64)
            gemm_f32<0, 64, 4><<<dim3(64 / 64, kM / 128), thr, 0, stream>>>(
                xcb, 512, xproj_w + (size_t)ed * 64 * 512, dbl, 64,
                nullptr, nullptr, 512);
            // dt-proj: (kM x 32, lda=64) @ (512 x 32)^T -> dtb, softplus
            gemm_f32<1, 128, 8><<<dim3(512 / 128, kM / 128), thr, 0, stream>>>(
                dbl, 64, dt_w + (size_t)ed * 512 * 32, dtb, 512,
                dt_b + (size_t)ed * 512, nullptr, 32);
            // chunked scan
            scan_chunk<<<dim3(kB * kNC * 2), thr, 0, stream>>>(
                dtb, xcb, dbl, A_log + (size_t)ed * kDI * kDS, Sb, sdt, dir);
            scan_carry<<<dim3(kB * kDI / 256), thr, 0, stream>>>(
                Sb, sdt, A_log + (size_t)ed * kDI * kDS, h0b);
            scan_emit<<<dim3(kB * kNC * 2), thr, 0, stream>>>(
                dtb, xcb, dbl, A_log + (size_t)ed * kDI * kDS, h0b,
                Dp + (size_t)ed * kDI, xz, yb, dir);
            // out-proj accumulate into residual x
            gemm_f32<2, 128, 8><<<dim3(512 / 128, kM / 128), thr, 0, stream>>>(
                yb, 512, out_w + (size_t)ed * 512 * 512, xcur, 512,
                nullptr, nullptr, 512);
        }
        // LN1 -> xn
        ln_k<<<dim3(kM), dim3(128), 0, stream>>>(
            xcur, ln1_g + e * kDM, ln1_b + e * kDM, xn);
        // FFN1: gelu(xn @ w1^T + b1) -> Hb (kM x 2048)
        gemm_f32<3, 128, 8><<<dim3(kDFF / 128, kM / 128), thr, 0, stream>>>(
            xn, 512, ff_w1 + (size_t)e * kDFF * kDM, Hb, kDFF,
            ff_b1 + (size_t)e * kDFF, nullptr, 512);
        // FFN2: Hb @ w2^T + b2 + xn -> t2
        gemm_f32<4, 128, 8><<<dim3(512 / 128, kM / 128), thr, 0, stream>>>(
            Hb, kDFF, ff_w2 + (size_t)e * kDM * kDFF, t2, 512,
            ff_b2 + (size_t)e * kDM, xn, kDFF);
        // LN2 -> x
        ln_k<<<dim3(kM), dim3(128), 0, stream>>>(
            t2, ln2_g + e * kDM, ln2_b + e * kDM, xcur);
    }
    // final LN (in-place safe)
    ln_k<<<dim3(kM), dim3(128), 0, stream>>>(xcur, lnf_g, lnf_b, xcur);
}

// Round 2
// 1781.628 us; speedup vs baseline: 2.2206x; 2.2206x over previous
//
#include <hip/hip_runtime.h>
#include <hip/hip_bf16.h>
#include <math.h>

#define DEVI __device__ __forceinline__

namespace {
constexpr int kL   = 1024;
constexpr int kDM  = 512;
constexpr int kDS  = 16;
constexpr int kDFF = 2048;
constexpr int kR   = 32;
constexpr int kDI  = 512;
constexpr int kB   = 16;
constexpr int kM   = kB * kL;     // 16384 rows
constexpr int kNC  = 32;          // scan chunks
constexpr int kCH  = kL / kNC;    // 32 steps per chunk
}

typedef __attribute__((ext_vector_type(8))) short short8;
typedef __attribute__((ext_vector_type(4))) float f32x4;

DEVI float silu_f(float x)     { return x / (1.f + __expf(-x)); }
DEVI float softplus_f(float x) { return fmaxf(x, 0.f) + log1pf(__expf(-fabsf(x))); }
DEVI float gelu_f(float x)     { return 0.5f * x * (1.f + erff(x * 0.70710678118654752f)); }

DEVI unsigned short f2bf(float f) {
    unsigned int u = __float_as_uint(f);
    return (unsigned short)((u + 0x7fffu + ((u >> 16) & 1u)) >> 16);
}
DEVI uint2 pack4(float4 v) {
    uint2 p;
    p.x = (unsigned int)f2bf(v.x) | ((unsigned int)f2bf(v.y) << 16);
    p.y = (unsigned int)f2bf(v.z) | ((unsigned int)f2bf(v.w) << 16);
    return p;
}

// ---------------------------------------------------------------------------
// bf16 MFMA GEMM:  C[m,n] = epi( sum_k A[m*lda+k] * W[n*Kd+k] )
// f32 inputs, converted to bf16 while staging to LDS; f32 accumulate.
// 128 x BN tile (BN = 64 or 128), BK=32, 256 threads = 4 waves (2x2),
// per-wave 64 x BN/2 output = 4 x NF fragments of 16x16.
// EPI: 0 plain, 2 accumulate, 3 bias+gelu, 4 bias+add.
// ---------------------------------------------------------------------------
template <int EPI, int BN>
__global__ __launch_bounds__(256) void gemm_mfma(
    const float* __restrict__ A, int lda,
    const float* __restrict__ W,
    float* __restrict__ C, int ldc,
    const float* __restrict__ bias, const float* __restrict__ add,
    int Kd)
{
    static_assert(BN == 64 || BN == 128, "");
    constexpr int LP = 40;           // padded LDS row (bf16 elems): 80B stride
    constexpr int NF = BN / 32;      // N fragments per wave
    __shared__ alignas(16) unsigned short As[2][128 * LP];
    __shared__ alignas(16) unsigned short Ws[2][BN * LP];

    const int tid  = threadIdx.x;
    const int lane = tid & 63;
    const int wv   = tid >> 6;
    const int wm   = wv >> 1;
    const int wn   = wv & 1;
    const int row0 = blockIdx.y * 128;
    const int col0 = blockIdx.x * BN;

    f32x4 acc[4][NF];
#pragma unroll
    for (int m = 0; m < 4; ++m)
#pragma unroll
        for (int n = 0; n < NF; ++n) acc[m][n] = (f32x4){0.f, 0.f, 0.f, 0.f};

    const int srw = tid >> 3;        // staging row within 32-row group
    const int skg = tid & 7;         // staging k-group (4 f32 each)
    const float* Ag = A + (size_t)(row0 + srw) * lda + skg * 4;
    const float* Wg = W + (size_t)(col0 + srw) * Kd + skg * 4;

    float4 av[4], wvv[NF];
    auto load_tile = [&](int k0) {
#pragma unroll
        for (int i = 0; i < 4; ++i)
            av[i] = *(const float4*)(Ag + (size_t)(32 * i) * lda + k0);
#pragma unroll
        for (int i = 0; i < NF; ++i)
            wvv[i] = *(const float4*)(Wg + (size_t)(32 * i) * Kd + k0);
    };
    auto write_tile = [&](int buf) {
#pragma unroll
        for (int i = 0; i < 4; ++i)
            *(uint2*)&As[buf][(srw + 32 * i) * LP + skg * 4] = pack4(av[i]);
#pragma unroll
        for (int i = 0; i < NF; ++i)
            *(uint2*)&Ws[buf][(srw + 32 * i) * LP + skg * 4] = pack4(wvv[i]);
    };

    const int nt = Kd / 32;
    load_tile(0);
    write_tile(0);
    __syncthreads();

    const int ak = (lane >> 4) * 8;   // k-offset (elems) of this lane's frag
    const int am = lane & 15;         // row (A) / col (B) index within frag

    int cur = 0;
    for (int t = 0; t < nt; ++t) {
        if (t + 1 < nt) load_tile((t + 1) * 32);   // prefetch into regs
        short8 af[4], bfr[NF];
#pragma unroll
        for (int m = 0; m < 4; ++m)
            af[m] = *(const short8*)&As[cur][(wm * 64 + m * 16 + am) * LP + ak];
#pragma unroll
        for (int n = 0; n < NF; ++n)
            bfr[n] = *(const short8*)&Ws[cur][(wn * (BN / 2) + n * 16 + am) * LP + ak];
#pragma unroll
        for (int m = 0; m < 4; ++m)
#pragma unroll
            for (int n = 0; n < NF; ++n)
                acc[m][n] = __builtin_amdgcn_mfma_f32_16x16x32_bf16(
                    af[m], bfr[n], acc[m][n], 0, 0, 0);
        __syncthreads();
        if (t + 1 < nt) write_tile(cur ^ 1);
        __syncthreads();
        cur ^= 1;
    }

    // epilogue: D[row=(lane>>4)*4+r][col=lane&15] per fragment
    const int cr = (lane >> 4) * 4;
#pragma unroll
    for (int m = 0; m < 4; ++m) {
#pragma unroll
        for (int n = 0; n < NF; ++n) {
            int cn = col0 + wn * (BN / 2) + n * 16 + am;
#pragma unroll
            for (int r = 0; r < 4; ++r) {
                int rr = row0 + wm * 64 + m * 16 + cr + r;
                size_t idx = (size_t)rr * ldc + cn;
                float v = acc[m][n][r];
                if constexpr (EPI == 0) {
                    C[idx] = v;
                } else if constexpr (EPI == 2) {
                    C[idx] += v;
                } else if constexpr (EPI == 3) {
                    C[idx] = gelu_f(v + bias[cn]);
                } else {
                    C[idx] = v + bias[cn] + add[idx];
                }
            }
        }
    }
}

// ---------------------------------------------------------------------------
// f32 vector GEMM (kept for dt-proj only: K=32). EPI 1: bias+softplus.
// ---------------------------------------------------------------------------
template <int EPI, int BN, int TN>
__global__ __launch_bounds__(256) void gemm_f32(
    const float* __restrict__ A, int lda,
    const float* __restrict__ W,
    float* __restrict__ C, int ldc,
    const float* __restrict__ bias, const float* __restrict__ add,
    int Kd)
{
    __shared__ float As[16][132];
    __shared__ float Ws[16][BN + 4];
    const int tid  = threadIdx.x;
    const int tx   = tid & 15;
    const int ty   = tid >> 4;
    const int row0 = blockIdx.y * 128;
    const int col0 = blockIdx.x * BN;
    const int lr   = tid >> 2;
    const int lc   = (tid & 3) << 2;

    float acc[8][TN];
#pragma unroll
    for (int i = 0; i < 8; ++i)
#pragma unroll
        for (int j = 0; j < TN; ++j) acc[i][j] = 0.f;

    const float* Arow0 = A + (size_t)(row0 + lr) * lda + lc;
    const float* Arow1 = A + (size_t)(row0 + lr + 64) * lda + lc;
    const float* Wrow0 = W + (size_t)(col0 + lr) * Kd + lc;
    const float* Wrow1 = W + (size_t)(col0 + lr + 64) * Kd + lc;

    for (int k0 = 0; k0 < Kd; k0 += 16) {
        float4 a0 = *(const float4*)(Arow0 + k0);
        float4 a1 = *(const float4*)(Arow1 + k0);
        float4 w0 = *(const float4*)(Wrow0 + k0);
        float4 w1;
        if (BN == 128) w1 = *(const float4*)(Wrow1 + k0);
        __syncthreads();
        As[lc + 0][lr]      = a0.x; As[lc + 1][lr]      = a0.y;
        As[lc + 2][lr]      = a0.z; As[lc + 3][lr]      = a0.w;
        As[lc + 0][lr + 64] = a1.x; As[lc + 1][lr + 64] = a1.y;
        As[lc + 2][lr + 64] = a1.z; As[lc + 3][lr + 64] = a1.w;
        Ws[lc + 0][lr]      = w0.x; Ws[lc + 1][lr]      = w0.y;
        Ws[lc + 2][lr]      = w0.z; Ws[lc + 3][lr]      = w0.w;
        if (BN == 128) {
            Ws[lc + 0][lr + 64] = w1.x; Ws[lc + 1][lr + 64] = w1.y;
            Ws[lc + 2][lr + 64] = w1.z; Ws[lc + 3][lr + 64] = w1.w;
        }
        __syncthreads();
#pragma unroll
        for (int kk = 0; kk < 16; ++kk) {
            float4 av0 = *(const float4*)&As[kk][ty * 8];
            float4 av1 = *(const float4*)&As[kk][ty * 8 + 4];
            float am[8] = {av0.x, av0.y, av0.z, av0.w, av1.x, av1.y, av1.z, av1.w};
            float bn[TN];
            float4 bv0 = *(const float4*)&Ws[kk][tx * TN];
            bn[0] = bv0.x; bn[1] = bv0.y; bn[2] = bv0.z; bn[3] = bv0.w;
            if (TN == 8) {
                float4 bv1 = *(const float4*)&Ws[kk][tx * TN + 4];
                bn[4] = bv1.x; bn[5] = bv1.y; bn[6] = bv1.z; bn[7] = bv1.w;
            }
#pragma unroll
            for (int i = 0; i < 8; ++i)
#pragma unroll
                for (int j = 0; j < TN; ++j)
                    acc[i][j] = fmaf(am[i], bn[j], acc[i][j]);
        }
    }

#pragma unroll
    for (int i = 0; i < 8; ++i) {
        int r = row0 + ty * 8 + i;
#pragma unroll
        for (int j = 0; j < TN; ++j) {
            int cn = col0 + tx * TN + j;
            size_t idx = (size_t)r * ldc + cn;
            float v = acc[i][j];
            if constexpr (EPI == 1) {
                C[idx] = softplus_f(v + bias[cn]);
            } else {
                C[idx] = v;
            }
        }
    }
}

// ---------------------------------------------------------------------------
// Depthwise causal/anti-causal conv (K=4) + bias + silu.
// ---------------------------------------------------------------------------
__global__ __launch_bounds__(256) void conv_silu_k(
    const float* __restrict__ xz, float* __restrict__ xc,
    const float* __restrict__ w, const float* __restrict__ bias, int dir)
{
    int idx = blockIdx.x * 256 + threadIdx.x;
    if (idx >= kM * kDI) return;
    int d   = idx & (kDI - 1);
    int row = idx >> 9;
    int t   = row & (kL - 1);
    int b   = row >> 10;
    float acc = bias[d];
#pragma unroll
    for (int k = 0; k < 4; ++k) {
        int tt = dir ? (t + 3 - k) : (t - 3 + k);
        if (tt >= 0 && tt < kL)
            acc = fmaf(w[d * 4 + k], xz[(size_t)(b * kL + tt) * 1024 + d], acc);
    }
    xc[idx] = silu_f(acc);
}

// ---------------------------------------------------------------------------
// Chunked selective scan.
// ---------------------------------------------------------------------------
__global__ __launch_bounds__(256) void scan_chunk(
    const float* __restrict__ dtb, const float* __restrict__ xcb,
    const float* __restrict__ dbl, const float* __restrict__ A_log,
    float* __restrict__ S, float* __restrict__ sdt, int dir)
{
    int blk  = blockIdx.x;
    int dblk = blk & 1;
    int c    = (blk >> 1) & (kNC - 1);
    int b    = blk >> 6;
    int d    = dblk * 256 + threadIdx.x;

    const float* al = A_log + d * kDS;
    float A[16];
#pragma unroll
    for (int s = 0; s < 16; ++s) A[s] = -__expf(al[s]);

    float h[16];
#pragma unroll
    for (int s = 0; s < 16; ++s) h[s] = 0.f;
    float sum = 0.f;

    for (int i = 0; i < kCH; ++i) {
        int p   = c * kCH + i;
        int t   = dir ? (kL - 1 - p) : p;
        int row = b * kL + t;
        float dt = dtb[(size_t)row * kDI + d];
        float xv = xcb[(size_t)row * kDI + d];
        sum += dt;
        float dx = dt * xv;
        const float4* bp = (const float4*)(dbl + (size_t)row * 64 + kR);
        float4 b0 = bp[0], b1 = bp[1], b2 = bp[2], b3 = bp[3];
        float Bv[16] = {b0.x, b0.y, b0.z, b0.w, b1.x, b1.y, b1.z, b1.w,
                        b2.x, b2.y, b2.z, b2.w, b3.x, b3.y, b3.z, b3.w};
#pragma unroll
        for (int s = 0; s < 16; ++s) {
            float q = __expf(dt * A[s]);
            h[s] = fmaf(q, h[s], dx * Bv[s]);
        }
    }
    size_t base = (size_t)(b * kNC + c) * kDS * kDI + d;
#pragma unroll
    for (int s = 0; s < 16; ++s) S[base + s * kDI] = h[s];
    sdt[(size_t)(b * kNC + c) * kDI + d] = sum;
}

__global__ __launch_bounds__(256) void scan_carry(
    const float* __restrict__ S, const float* __restrict__ sdt,
    const float* __restrict__ A_log, float* __restrict__ h0)
{
    int g = blockIdx.x * 256 + threadIdx.x;
    int b = g >> 9;
    int d = g & (kDI - 1);
    const float* al = A_log + d * kDS;
    float A[16];
#pragma unroll
    for (int s = 0; s < 16; ++s) A[s] = -__expf(al[s]);
    float h[16];
#pragma unroll
    for (int s = 0; s < 16; ++s) h[s] = 0.f;

    for (int c = 0; c < kNC; ++c) {
        size_t base = (size_t)(b * kNC + c) * kDS * kDI + d;
        float sd = sdt[(size_t)(b * kNC + c) * kDI + d];
#pragma unroll
        for (int s = 0; s < 16; ++s) {
            h0[base + s * kDI] = h[s];
            float P = __expf(sd * A[s]);
            h[s] = fmaf(P, h[s], S[base + s * kDI]);
        }
    }
}

__global__ __launch_bounds__(256) void scan_emit(
    const float* __restrict__ dtb, const float* __restrict__ xcb,
    const float* __restrict__ dbl, const float* __restrict__ A_log,
    const float* __restrict__ h0v, const float* __restrict__ Dp,
    const float* __restrict__ xz, float* __restrict__ yb, int dir)
{
    int blk  = blockIdx.x;
    int dblk = blk & 1;
    int c    = (blk >> 1) & (kNC - 1);
    int b    = blk >> 6;
    int d    = dblk * 256 + threadIdx.x;

    const float* al = A_log + d * kDS;
    float A[16];
#pragma unroll
    for (int s = 0; s < 16; ++s) A[s] = -__expf(al[s]);
    float Dd = Dp[d];

    size_t hbase = (size_t)(b * kNC + c) * kDS * kDI + d;
    float h[16];
#pragma unroll
    for (int s = 0; s < 16; ++s) h[s] = h0v[hbase + s * kDI];

    for (int i = 0; i < kCH; ++i) {
        int p   = c * kCH + i;
        int t   = dir ? (kL - 1 - p) : p;
        int row = b * kL + t;
        float dt = dtb[(size_t)row * kDI + d];
        float xv = xcb[(size_t)row * kDI + d];
        float dx = dt * xv;
        const float4* bp = (const float4*)(dbl + (size_t)row * 64 + kR);
        float4 b0 = bp[0], b1 = bp[1], b2 = bp[2], b3 = bp[3];
        const float4* cp = (const float4*)(dbl + (size_t)row * 64 + kR + kDS);
        float4 c0 = cp[0], c1 = cp[1], c2 = cp[2], c3 = cp[3];
        float Bv[16] = {b0.x, b0.y, b0.z, b0.w, b1.x, b1.y, b1.z, b1.w,
                        b2.x, b2.y, b2.z, b2.w, b3.x, b3.y, b3.z, b3.w};
        float Cv[16] = {c0.x, c0.y, c0.z, c0.w, c1.x, c1.y, c1.z, c1.w,
                        c2.x, c2.y, c2.z, c2.w, c3.x, c3.y, c3.z, c3.w};
        float y = 0.f;
#pragma unroll
        for (int s = 0; s < 16; ++s) {
            float q = __expf(dt * A[s]);
            h[s] = fmaf(q, h[s], dx * Bv[s]);
            y = fmaf(h[s], Cv[s], y);
        }
        y += xv * Dd;
        float z = xz[(size_t)row * 1024 + 512 + d];
        yb[(size_t)row * kDI + d] = y * silu_f(z);
    }
}

// ---------------------------------------------------------------------------
// LayerNorm over rows of 512.
// ---------------------------------------------------------------------------
__global__ __launch_bounds__(128) void ln_k(
    const float* __restrict__ in, const float* __restrict__ g,
    const float* __restrict__ bb, float* __restrict__ out)
{
    int row = blockIdx.x;
    int tid = threadIdx.x;
    float4 v = *(const float4*)&in[(size_t)row * kDM + tid * 4];
    float s1 = v.x + v.y + v.z + v.w;
    float s2 = v.x * v.x + v.y * v.y + v.z * v.z + v.w * v.w;
#pragma unroll
    for (int off = 32; off >= 1; off >>= 1) {
        s1 += __shfl_xor(s1, off);
        s2 += __shfl_xor(s2, off);
    }
    __shared__ float red[4];
    if ((tid & 63) == 0) { red[(tid >> 6) * 2] = s1; red[(tid >> 6) * 2 + 1] = s2; }
    __syncthreads();
    s1 = red[0] + red[2];
    s2 = red[1] + red[3];
    float mu  = s1 * (1.f / kDM);
    float var = s2 * (1.f / kDM) - mu * mu;
    float rs  = rsqrtf(var + 1e-5f);
    int cn = tid * 4;
    float4 gv = *(const float4*)&g[cn];
    float4 bv = *(const float4*)&bb[cn];
    float4 o;
    o.x = (v.x - mu) * rs * gv.x + bv.x;
    o.y = (v.y - mu) * rs * gv.y + bv.y;
    o.z = (v.z - mu) * rs * gv.z + bv.z;
    o.w = (v.w - mu) * rs * gv.w + bv.w;
    *(float4*)&out[(size_t)row * kDM + cn] = o;
}

// ---------------------------------------------------------------------------
extern "C" void kernel_launch(void* const* d_in, const int* in_sizes, int n_in,
                              void* d_out, int out_size, void* d_ws, size_t ws_size,
                              hipStream_t stream)
{
    const float* x_in    = (const float*)d_in[0];
    const float* in_w    = (const float*)d_in[1];
    const float* conv_w  = (const float*)d_in[2];
    const float* conv_b  = (const float*)d_in[3];
    const float* xproj_w = (const float*)d_in[4];
    const float* dt_w    = (const float*)d_in[5];
    const float* dt_b    = (const float*)d_in[6];
    const float* A_log   = (const float*)d_in[7];
    const float* Dp      = (const float*)d_in[8];
    const float* out_w   = (const float*)d_in[9];
    const float* ff_w1   = (const float*)d_in[10];
    const float* ff_b1   = (const float*)d_in[11];
    const float* ff_w2   = (const float*)d_in[12];
    const float* ff_b2   = (const float*)d_in[13];
    const float* ln1_g   = (const float*)d_in[14];
    const float* ln1_b   = (const float*)d_in[15];
    const float* ln2_g   = (const float*)d_in[16];
    const float* ln2_b   = (const float*)d_in[17];
    const float* lnf_g   = (const float*)d_in[18];
    const float* lnf_b   = (const float*)d_in[19];

    float* ws = (float*)d_ws;
    float* xz  = ws;                   // kM x 1024
    float* xcb = ws + 16777216;        // kM x 512
    float* dtb = ws + 25165824;        // kM x 512
    float* dbl = ws + 33554432;        // kM x 64
    float* yb  = ws + 34603008;        // kM x 512
    float* Sb  = ws + 42991616;
    float* h0b = ws + 47185920;
    float* sdt = ws + 51380224;
    float* xn  = ws + 42991616;        // ffn-phase alias
    float* Hb  = ws;                   // ffn-phase alias (kM x 2048)
    float* t2  = ws + 33554432;        // ffn-phase alias

    float* xcur = (float*)d_out;

    hipMemcpyAsync(xcur, x_in, (size_t)kM * kDM * sizeof(float),
                   hipMemcpyDeviceToDevice, stream);

    dim3 thr(256);
    for (int e = 0; e < 2; ++e) {
        for (int dir = 0; dir < 2; ++dir) {
            int ed = e * 2 + dir;
            // in-proj: (kM x 512) @ (1024 x 512)^T -> xz
            gemm_mfma<0, 128><<<dim3(1024 / 128, kM / 128), thr, 0, stream>>>(
                xcur, 512, in_w + (size_t)ed * 1024 * 512, xz, 1024,
                nullptr, nullptr, 512);
            conv_silu_k<<<dim3(kM * kDI / 256), thr, 0, stream>>>(
                xz, xcb, conv_w + (size_t)ed * kDI * 4, conv_b + (size_t)ed * kDI, dir);
            // x-proj: (kM x 512) @ (64 x 512)^T -> dbl
            gemm_mfma<0, 64><<<dim3(1, kM / 128), thr, 0, stream>>>(
                xcb, 512, xproj_w + (size_t)ed * 64 * 512, dbl, 64,
                nullptr, nullptr, 512);
            // dt-proj: (kM x 32, lda=64) @ (512 x 32)^T -> dtb, softplus (f32)
            gemm_f32<1, 128, 8><<<dim3(512 / 128, kM / 128), thr, 0, stream>>>(
                dbl, 64, dt_w + (size_t)ed * 512 * 32, dtb, 512,
                dt_b + (size_t)ed * 512, nullptr, 32);
            // chunked scan
            scan_chunk<<<dim3(kB * kNC * 2), thr, 0, stream>>>(
                dtb, xcb, dbl, A_log + (size_t)ed * kDI * kDS, Sb, sdt, dir);
            scan_carry<<<dim3(kB * kDI / 256), thr, 0, stream>>>(
                Sb, sdt, A_log + (size_t)ed * kDI * kDS, h0b);
            scan_emit<<<dim3(kB * kNC * 2), thr, 0, stream>>>(
                dtb, xcb, dbl, A_log + (size_t)ed * kDI * kDS, h0b,
                Dp + (size_t)ed * kDI, xz, yb, dir);
            // out-proj accumulate into residual x
            gemm_mfma<2, 128><<<dim3(512 / 128, kM / 128), thr, 0, stream>>>(
                yb, 512, out_w + (size_t)ed * 512 * 512, xcur, 512,
                nullptr, nullptr, 512);
        }
        ln_k<<<dim3(kM), dim3(128), 0, stream>>>(
            xcur, ln1_g + e * kDM, ln1_b + e * kDM, xn);
        // FFN1: gelu(xn @ w1^T + b1) -> Hb
        gemm_mfma<3, 128><<<dim3(kDFF / 128, kM / 128), thr, 0, stream>>>(
            xn, 512, ff_w1 + (size_t)e * kDFF * kDM, Hb, kDFF,
            ff_b1 + (size_t)e * kDFF, nullptr, 512);
        // FFN2: Hb @ w2^T + b2 + xn -> t2
        gemm_mfma<4, 128><<<dim3(512 / 128, kM / 128), thr, 0, stream>>>(
            Hb, kDFF, ff_w2 + (size_t)e * kDM * kDFF, t2, 512,
            ff_b2 + (size_t)e * kDM, xn, 2048);
        ln_k<<<dim3(kM), dim3(128), 0, stream>>>(
            t2, ln2_g + e * kDM, ln2_b + e * kDM, xcur);
    }
    ln_k<<<dim3(kM), dim3(128), 0, stream>>>(xcur, lnf_g, lnf_b, xcur);
}

// Round 3
// 1363.075 us; speedup vs baseline: 2.9024x; 1.3071x over previous
//
#include <hip/hip_runtime.h>
#include <hip/hip_bf16.h>
#include <math.h>

#define DEVI __device__ __forceinline__

namespace {
constexpr int kL   = 1024;
constexpr int kDM  = 512;
constexpr int kDS  = 16;
constexpr int kDFF = 2048;
constexpr int kR   = 32;
constexpr int kDI  = 512;
constexpr int kB   = 16;
constexpr int kM   = kB * kL;     // 16384 rows
constexpr int kNC  = 32;          // scan chunks
constexpr int kCH  = kL / kNC;    // 32 steps per chunk
}

typedef __attribute__((ext_vector_type(8))) short short8;
typedef __attribute__((ext_vector_type(4))) float f32x4;

DEVI float silu_f(float x)     { return x / (1.f + __expf(-x)); }
DEVI float softplus_f(float x) { return fmaxf(x, 0.f) + log1pf(__expf(-fabsf(x))); }
DEVI float gelu_f(float x)     { return 0.5f * x * (1.f + erff(x * 0.70710678118654752f)); }

DEVI unsigned short f2bf(float f) {
    unsigned int u = __float_as_uint(f);
    return (unsigned short)((u + 0x7fffu + ((u >> 16) & 1u)) >> 16);
}
DEVI float bf2f(unsigned short u) {
    return __uint_as_float(((unsigned int)u) << 16);
}
DEVI uint2 pack4(float4 v) {
    uint2 p;
    p.x = (unsigned int)f2bf(v.x) | ((unsigned int)f2bf(v.y) << 16);
    p.y = (unsigned int)f2bf(v.z) | ((unsigned int)f2bf(v.w) << 16);
    return p;
}

typedef const __attribute__((address_space(1))) unsigned int* gas1;
typedef __attribute__((address_space(3))) unsigned int* las3;
DEVI void gload16(const unsigned short* g, unsigned short* l) {
    __builtin_amdgcn_global_load_lds((gas1)g, (las3)l, 16, 0, 0);
}

// ---------------------------------------------------------------------------
// f32 -> bf16 conversion (4 elems/thread)
// ---------------------------------------------------------------------------
__global__ __launch_bounds__(256) void cvt_f2b_k(
    const float* __restrict__ in, unsigned short* __restrict__ out, int n4)
{
    int i = blockIdx.x * 256 + threadIdx.x;
    if (i >= n4) return;
    float4 v = *(const float4*)&in[(size_t)i * 4];
    *(uint2*)&out[(size_t)i * 4] = pack4(v);
}

// ---------------------------------------------------------------------------
// bf16 MFMA GEMM, m97-style: global_load_lds staging, linear LDS [rows][32],
// double-buffered, 1 barrier per K-step. 128 x BN tile, BK=32, 4 waves (2x2).
// EPI: 0 plain store (CT: ushort=bf16 or float), 2 accumulate f32,
//      3 bias+gelu (bf16 out), 4 bias+add (f32 out).
// A: (M x Kd) bf16 row-major, lda elems. W: (N x Kd) bf16 row-major.
// ---------------------------------------------------------------------------
template <int EPI, int BN, typename CT>
__global__ __launch_bounds__(256) void gemm_bf16(
    const unsigned short* __restrict__ A, int lda,
    const unsigned short* __restrict__ W,
    CT* __restrict__ C, int ldc,
    const float* __restrict__ bias, const float* __restrict__ add,
    int Kd)
{
    static_assert(BN == 64 || BN == 128, "");
    constexpr int NF = BN / 32;
    __shared__ alignas(16) unsigned short As[2][128 * 32];
    __shared__ alignas(16) unsigned short Ws[2][BN * 32];

    // XCD-aware swizzle of the flat block index (contiguous chunk per XCD)
    const int gx = gridDim.x;
    int flat = blockIdx.y * gx + blockIdx.x;
    const int total = gx * gridDim.y;
    if ((total & 7) == 0) {
        int q = total >> 3;
        flat = (flat & 7) * q + (flat >> 3);
    }
    const int bx = flat % gx;
    const int by = flat / gx;

    const int tid  = threadIdx.x;
    const int lane = tid & 63;
    const int wv   = tid >> 6;
    const int wm   = wv >> 1;
    const int wn   = wv & 1;
    const int row0 = by * 128;
    const int col0 = bx * BN;

    f32x4 acc[4][NF];
#pragma unroll
    for (int m = 0; m < 4; ++m)
#pragma unroll
        for (int n = 0; n < NF; ++n) acc[m][n] = (f32x4){0.f, 0.f, 0.f, 0.f};

    const int sr = tid >> 2;            // staging row (0..63)
    const int sc = (tid & 3) * 8;       // staging col (8 bf16 = 16B)
    const unsigned short* Ag = A + (size_t)(row0 + sr) * lda + sc;
    const unsigned short* Wg = W + (size_t)(col0 + sr) * Kd + sc;

    auto stage = [&](int buf, int k0) {
        gload16(Ag + k0, &As[buf][tid * 8]);
        gload16(Ag + (size_t)64 * lda + k0, &As[buf][2048 + tid * 8]);
        gload16(Wg + k0, &Ws[buf][tid * 8]);
        if (BN == 128)
            gload16(Wg + (size_t)64 * Kd + k0, &Ws[buf][2048 + tid * 8]);
    };

    const int nt = Kd / 32;
    stage(0, 0);
    __syncthreads();

    const int fr = lane & 15;           // frag row/col
    const int fk = (lane >> 4) * 8;     // frag k offset

    int cur = 0;
    for (int t = 0; t < nt; ++t) {
        if (t + 1 < nt) stage(cur ^ 1, (t + 1) * 32);
        short8 af[4], bf[NF];
#pragma unroll
        for (int m = 0; m < 4; ++m)
            af[m] = *(const short8*)&As[cur][(wm * 64 + m * 16 + fr) * 32 + fk];
#pragma unroll
        for (int n = 0; n < NF; ++n)
            bf[n] = *(const short8*)&Ws[cur][(wn * (BN / 2) + n * 16 + fr) * 32 + fk];
#pragma unroll
        for (int m = 0; m < 4; ++m)
#pragma unroll
            for (int n = 0; n < NF; ++n)
                acc[m][n] = __builtin_amdgcn_mfma_f32_16x16x32_bf16(
                    af[m], bf[n], acc[m][n], 0, 0, 0);
        __syncthreads();
        cur ^= 1;
    }

    const int cr = (lane >> 4) * 4;
#pragma unroll
    for (int m = 0; m < 4; ++m) {
#pragma unroll
        for (int n = 0; n < NF; ++n) {
            int cn = col0 + wn * (BN / 2) + n * 16 + fr;
#pragma unroll
            for (int r = 0; r < 4; ++r) {
                int rr = row0 + wm * 64 + m * 16 + cr + r;
                size_t idx = (size_t)rr * ldc + cn;
                float v = acc[m][n][r];
                if constexpr (EPI == 0) {
                    if constexpr (__is_same(CT, unsigned short)) C[idx] = f2bf(v);
                    else C[idx] = v;
                } else if constexpr (EPI == 2) {
                    C[idx] += v;
                } else if constexpr (EPI == 3) {
                    C[idx] = f2bf(gelu_f(v + bias[cn]));
                } else {
                    C[idx] = v + bias[cn] + add[idx];
                }
            }
        }
    }
}

// ---------------------------------------------------------------------------
// f32 vector GEMM for dt-proj (K=32). EPI 1: bias+softplus.
// ---------------------------------------------------------------------------
template <int EPI, int BN, int TN>
__global__ __launch_bounds__(256) void gemm_f32(
    const float* __restrict__ A, int lda,
    const float* __restrict__ W,
    float* __restrict__ C, int ldc,
    const float* __restrict__ bias, const float* __restrict__ add,
    int Kd)
{
    __shared__ float As[16][132];
    __shared__ float Ws[16][BN + 4];
    const int tid  = threadIdx.x;
    const int tx   = tid & 15;
    const int ty   = tid >> 4;
    const int row0 = blockIdx.y * 128;
    const int col0 = blockIdx.x * BN;
    const int lr   = tid >> 2;
    const int lc   = (tid & 3) << 2;

    float acc[8][TN];
#pragma unroll
    for (int i = 0; i < 8; ++i)
#pragma unroll
        for (int j = 0; j < TN; ++j) acc[i][j] = 0.f;

    const float* Arow0 = A + (size_t)(row0 + lr) * lda + lc;
    const float* Arow1 = A + (size_t)(row0 + lr + 64) * lda + lc;
    const float* Wrow0 = W + (size_t)(col0 + lr) * Kd + lc;
    const float* Wrow1 = W + (size_t)(col0 + lr + 64) * Kd + lc;

    for (int k0 = 0; k0 < Kd; k0 += 16) {
        float4 a0 = *(const float4*)(Arow0 + k0);
        float4 a1 = *(const float4*)(Arow1 + k0);
        float4 w0 = *(const float4*)(Wrow0 + k0);
        float4 w1;
        if (BN == 128) w1 = *(const float4*)(Wrow1 + k0);
        __syncthreads();
        As[lc + 0][lr]      = a0.x; As[lc + 1][lr]      = a0.y;
        As[lc + 2][lr]      = a0.z; As[lc + 3][lr]      = a0.w;
        As[lc + 0][lr + 64] = a1.x; As[lc + 1][lr + 64] = a1.y;
        As[lc + 2][lr + 64] = a1.z; As[lc + 3][lr + 64] = a1.w;
        Ws[lc + 0][lr]      = w0.x; Ws[lc + 1][lr]      = w0.y;
        Ws[lc + 2][lr]      = w0.z; Ws[lc + 3][lr]      = w0.w;
        if (BN == 128) {
            Ws[lc + 0][lr + 64] = w1.x; Ws[lc + 1][lr + 64] = w1.y;
            Ws[lc + 2][lr + 64] = w1.z; Ws[lc + 3][lr + 64] = w1.w;
        }
        __syncthreads();
#pragma unroll
        for (int kk = 0; kk < 16; ++kk) {
            float4 av0 = *(const float4*)&As[kk][ty * 8];
            float4 av1 = *(const float4*)&As[kk][ty * 8 + 4];
            float am[8] = {av0.x, av0.y, av0.z, av0.w, av1.x, av1.y, av1.z, av1.w};
            float bn[TN];
            float4 bv0 = *(const float4*)&Ws[kk][tx * TN];
            bn[0] = bv0.x; bn[1] = bv0.y; bn[2] = bv0.z; bn[3] = bv0.w;
            if (TN == 8) {
                float4 bv1 = *(const float4*)&Ws[kk][tx * TN + 4];
                bn[4] = bv1.x; bn[5] = bv1.y; bn[6] = bv1.z; bn[7] = bv1.w;
            }
#pragma unroll
            for (int i = 0; i < 8; ++i)
#pragma unroll
                for (int j = 0; j < TN; ++j)
                    acc[i][j] = fmaf(am[i], bn[j], acc[i][j]);
        }
    }

#pragma unroll
    for (int i = 0; i < 8; ++i) {
        int r = row0 + ty * 8 + i;
#pragma unroll
        for (int j = 0; j < TN; ++j) {
            int cn = col0 + tx * TN + j;
            size_t idx = (size_t)r * ldc + cn;
            float v = acc[i][j];
            if constexpr (EPI == 1) {
                C[idx] = softplus_f(v + bias[cn]);
            } else {
                C[idx] = v;
            }
        }
    }
}

// ---------------------------------------------------------------------------
// Depthwise causal/anti-causal conv (K=4) + bias + silu. bf16 in/out.
// Each thread: 4 consecutive d.
// ---------------------------------------------------------------------------
__global__ __launch_bounds__(256) void conv_silu_k(
    const unsigned short* __restrict__ xz, unsigned short* __restrict__ xc,
    const float* __restrict__ w, const float* __restrict__ bias, int dir)
{
    int idx = blockIdx.x * 256 + threadIdx.x;     // kM*kDI/4 total
    if (idx >= kM * kDI / 4) return;
    int d0  = (idx & 127) * 4;
    int row = idx >> 7;
    int t   = row & (kL - 1);
    int b   = row >> 10;
    float acc[4];
#pragma unroll
    for (int j = 0; j < 4; ++j) acc[j] = bias[d0 + j];
#pragma unroll
    for (int k = 0; k < 4; ++k) {
        int tt = dir ? (t + 3 - k) : (t - 3 + k);
        if (tt >= 0 && tt < kL) {
            uint2 p = *(const uint2*)&xz[(size_t)(b * kL + tt) * 1024 + d0];
            float xv[4] = {bf2f((unsigned short)(p.x & 0xffff)),
                           bf2f((unsigned short)(p.x >> 16)),
                           bf2f((unsigned short)(p.y & 0xffff)),
                           bf2f((unsigned short)(p.y >> 16))};
#pragma unroll
            for (int j = 0; j < 4; ++j)
                acc[j] = fmaf(w[(d0 + j) * 4 + k], xv[j], acc[j]);
        }
    }
    uint2 o;
    o.x = (unsigned int)f2bf(silu_f(acc[0])) | ((unsigned int)f2bf(silu_f(acc[1])) << 16);
    o.y = (unsigned int)f2bf(silu_f(acc[2])) | ((unsigned int)f2bf(silu_f(acc[3])) << 16);
    *(uint2*)&xc[(size_t)row * kDI + d0] = o;
}

// ---------------------------------------------------------------------------
// Chunked selective scan (f32 state; bf16 xc/z streams).
// ---------------------------------------------------------------------------
__global__ __launch_bounds__(256) void scan_chunk(
    const float* __restrict__ dtb, const unsigned short* __restrict__ xcb,
    const float* __restrict__ dbl, const float* __restrict__ A_log,
    float* __restrict__ S, float* __restrict__ sdt, int dir)
{
    int blk  = blockIdx.x;
    int dblk = blk & 1;
    int c    = (blk >> 1) & (kNC - 1);
    int b    = blk >> 6;
    int d    = dblk * 256 + threadIdx.x;

    const float* al = A_log + d * kDS;
    float A[16];
#pragma unroll
    for (int s = 0; s < 16; ++s) A[s] = -__expf(al[s]);

    float h[16];
#pragma unroll
    for (int s = 0; s < 16; ++s) h[s] = 0.f;
    float sum = 0.f;

    for (int i = 0; i < kCH; ++i) {
        int p   = c * kCH + i;
        int t   = dir ? (kL - 1 - p) : p;
        int row = b * kL + t;
        float dt = dtb[(size_t)row * kDI + d];
        float xv = bf2f(xcb[(size_t)row * kDI + d]);
        sum += dt;
        float dx = dt * xv;
        const float4* bp = (const float4*)(dbl + (size_t)row * 64 + kR);
        float4 b0 = bp[0], b1 = bp[1], b2 = bp[2], b3 = bp[3];
        float Bv[16] = {b0.x, b0.y, b0.z, b0.w, b1.x, b1.y, b1.z, b1.w,
                        b2.x, b2.y, b2.z, b2.w, b3.x, b3.y, b3.z, b3.w};
#pragma unroll
        for (int s = 0; s < 16; ++s) {
            float q = __expf(dt * A[s]);
            h[s] = fmaf(q, h[s], dx * Bv[s]);
        }
    }
    size_t base = (size_t)(b * kNC + c) * kDS * kDI + d;
#pragma unroll
    for (int s = 0; s < 16; ++s) S[base + s * kDI] = h[s];
    sdt[(size_t)(b * kNC + c) * kDI + d] = sum;
}

__global__ __launch_bounds__(256) void scan_carry(
    const float* __restrict__ S, const float* __restrict__ sdt,
    const float* __restrict__ A_log, float* __restrict__ h0)
{
    int g = blockIdx.x * 256 + threadIdx.x;
    int b = g >> 9;
    int d = g & (kDI - 1);
    const float* al = A_log + d * kDS;
    float A[16];
#pragma unroll
    for (int s = 0; s < 16; ++s) A[s] = -__expf(al[s]);
    float h[16];
#pragma unroll
    for (int s = 0; s < 16; ++s) h[s] = 0.f;

    for (int c = 0; c < kNC; ++c) {
        size_t base = (size_t)(b * kNC + c) * kDS * kDI + d;
        float sd = sdt[(size_t)(b * kNC + c) * kDI + d];
#pragma unroll
        for (int s = 0; s < 16; ++s) {
            h0[base + s * kDI] = h[s];
            float P = __expf(sd * A[s]);
            h[s] = fmaf(P, h[s], S[base + s * kDI]);
        }
    }
}

__global__ __launch_bounds__(256) void scan_emit(
    const float* __restrict__ dtb, const unsigned short* __restrict__ xcb,
    const float* __restrict__ dbl, const float* __restrict__ A_log,
    const float* __restrict__ h0v, const float* __restrict__ Dp,
    const unsigned short* __restrict__ xz, unsigned short* __restrict__ yb, int dir)
{
    int blk  = blockIdx.x;
    int dblk = blk & 1;
    int c    = (blk >> 1) & (kNC - 1);
    int b    = blk >> 6;
    int d    = dblk * 256 + threadIdx.x;

    const float* al = A_log + d * kDS;
    float A[16];
#pragma unroll
    for (int s = 0; s < 16; ++s) A[s] = -__expf(al[s]);
    float Dd = Dp[d];

    size_t hbase = (size_t)(b * kNC + c) * kDS * kDI + d;
    float h[16];
#pragma unroll
    for (int s = 0; s < 16; ++s) h[s] = h0v[hbase + s * kDI];

    for (int i = 0; i < kCH; ++i) {
        int p   = c * kCH + i;
        int t   = dir ? (kL - 1 - p) : p;
        int row = b * kL + t;
        float dt = dtb[(size_t)row * kDI + d];
        float xv = bf2f(xcb[(size_t)row * kDI + d]);
        float dx = dt * xv;
        const float4* bp = (const float4*)(dbl + (size_t)row * 64 + kR);
        float4 b0 = bp[0], b1 = bp[1], b2 = bp[2], b3 = bp[3];
        const float4* cp = (const float4*)(dbl + (size_t)row * 64 + kR + kDS);
        float4 c0 = cp[0], c1 = cp[1], c2 = cp[2], c3 = cp[3];
        float Bv[16] = {b0.x, b0.y, b0.z, b0.w, b1.x, b1.y, b1.z, b1.w,
                        b2.x, b2.y, b2.z, b2.w, b3.x, b3.y, b3.z, b3.w};
        float Cv[16] = {c0.x, c0.y, c0.z, c0.w, c1.x, c1.y, c1.z, c1.w,
                        c2.x, c2.y, c2.z, c2.w, c3.x, c3.y, c3.z, c3.w};
        float y = 0.f;
#pragma unroll
        for (int s = 0; s < 16; ++s) {
            float q = __expf(dt * A[s]);
            h[s] = fmaf(q, h[s], dx * Bv[s]);
            y = fmaf(h[s], Cv[s], y);
        }
        y += xv * Dd;
        float z = bf2f(xz[(size_t)row * 1024 + 512 + d]);
        yb[(size_t)row * kDI + d] = f2bf(y * silu_f(z));
    }
}

// ---------------------------------------------------------------------------
// LayerNorm over rows of 512. Optional second bf16 output.
// ---------------------------------------------------------------------------
__global__ __launch_bounds__(128) void ln_k(
    const float* __restrict__ in, const float* __restrict__ g,
    const float* __restrict__ bb, float* __restrict__ out,
    unsigned short* __restrict__ outbf)
{
    int row = blockIdx.x;
    int tid = threadIdx.x;
    float4 v = *(const float4*)&in[(size_t)row * kDM + tid * 4];
    float s1 = v.x + v.y + v.z + v.w;
    float s2 = v.x * v.x + v.y * v.y + v.z * v.z + v.w * v.w;
#pragma unroll
    for (int off = 32; off >= 1; off >>= 1) {
        s1 += __shfl_xor(s1, off);
        s2 += __shfl_xor(s2, off);
    }
    __shared__ float red[4];
    if ((tid & 63) == 0) { red[(tid >> 6) * 2] = s1; red[(tid >> 6) * 2 + 1] = s2; }
    __syncthreads();
    s1 = red[0] + red[2];
    s2 = red[1] + red[3];
    float mu  = s1 * (1.f / kDM);
    float var = s2 * (1.f / kDM) - mu * mu;
    float rs  = rsqrtf(var + 1e-5f);
    int cn = tid * 4;
    float4 gv = *(const float4*)&g[cn];
    float4 bv = *(const float4*)&bb[cn];
    float4 o;
    o.x = (v.x - mu) * rs * gv.x + bv.x;
    o.y = (v.y - mu) * rs * gv.y + bv.y;
    o.z = (v.z - mu) * rs * gv.z + bv.z;
    o.w = (v.w - mu) * rs * gv.w + bv.w;
    *(float4*)&out[(size_t)row * kDM + cn] = o;
    if (outbf)
        *(uint2*)&outbf[(size_t)row * kDM + cn] = pack4(o);
}

// ---------------------------------------------------------------------------
extern "C" void kernel_launch(void* const* d_in, const int* in_sizes, int n_in,
                              void* d_out, int out_size, void* d_ws, size_t ws_size,
                              hipStream_t stream)
{
    const float* x_in    = (const float*)d_in[0];
    const float* in_w    = (const float*)d_in[1];
    const float* conv_w  = (const float*)d_in[2];
    const float* conv_b  = (const float*)d_in[3];
    const float* xproj_w = (const float*)d_in[4];
    const float* dt_w    = (const float*)d_in[5];
    const float* dt_b    = (const float*)d_in[6];
    const float* A_log   = (const float*)d_in[7];
    const float* Dp      = (const float*)d_in[8];
    const float* out_w   = (const float*)d_in[9];
    const float* ff_w1   = (const float*)d_in[10];
    const float* ff_b1   = (const float*)d_in[11];
    const float* ff_w2   = (const float*)d_in[12];
    const float* ff_b2   = (const float*)d_in[13];
    const float* ln1_g   = (const float*)d_in[14];
    const float* ln1_b   = (const float*)d_in[15];
    const float* ln2_g   = (const float*)d_in[16];
    const float* ln2_b   = (const float*)d_in[17];
    const float* lnf_g   = (const float*)d_in[18];
    const float* lnf_b   = (const float*)d_in[19];

    float* ws = (float*)d_ws;
    unsigned short* wsb = (unsigned short*)d_ws;

    // bf16 weight region (bf16-element offsets)
    unsigned short* wb_in  = wsb;                 // 2,097,152
    unsigned short* wb_xp  = wsb + 2097152;       //   131,072
    unsigned short* wb_out = wsb + 2228224;       // 1,048,576
    unsigned short* wb_f1  = wsb + 3276800;       // 2,097,152
    unsigned short* wb_f2  = wsb + 5373952;       // 2,097,152
    // arena base (f32 words): 3,735,552
    constexpr size_t A0 = 3735552;
    unsigned short* xbf = (unsigned short*)(ws + A0);
    unsigned short* xz  = (unsigned short*)(ws + A0 + 4194304);
    unsigned short* xcb = (unsigned short*)(ws + A0 + 12582912);
    float*          dtb = ws + A0 + 16777216;
    float*          dbl = ws + A0 + 25165824;
    unsigned short* yb  = (unsigned short*)(ws + A0 + 26214400);
    float*          Sb  = ws + A0 + 30408704;
    float*          h0b = ws + A0 + 34603008;
    float*          sdt = ws + A0 + 38797312;
    // ffn-phase aliases (mamba arena dead)
    float*          xn   = ws + A0;
    unsigned short* xnbf = (unsigned short*)(ws + A0 + 8388608);
    unsigned short* Hb   = (unsigned short*)(ws + A0 + 12582912);
    float*          t2   = ws + A0 + 29360128;

    float* xcur = (float*)d_out;

    hipMemcpyAsync(xcur, x_in, (size_t)kM * kDM * sizeof(float),
                   hipMemcpyDeviceToDevice, stream);

    dim3 thr(256);
    // one-time weight conversions
    cvt_f2b_k<<<dim3(2097152 / 1024), thr, 0, stream>>>(in_w, wb_in, 524288);
    cvt_f2b_k<<<dim3(131072 / 1024), thr, 0, stream>>>(xproj_w, wb_xp, 32768);
    cvt_f2b_k<<<dim3(1048576 / 1024), thr, 0, stream>>>(out_w, wb_out, 262144);
    cvt_f2b_k<<<dim3(2097152 / 1024), thr, 0, stream>>>(ff_w1, wb_f1, 524288);
    cvt_f2b_k<<<dim3(2097152 / 1024), thr, 0, stream>>>(ff_w2, wb_f2, 524288);

    for (int e = 0; e < 2; ++e) {
        // snapshot x -> bf16 (both mamba dirs read the same input)
        cvt_f2b_k<<<dim3(2097152 / 256), thr, 0, stream>>>(xcur, xbf, 2097152);
        for (int dir = 0; dir < 2; ++dir) {
            int ed = e * 2 + dir;
            // in-proj: (kM x 512) @ (1024 x 512)^T -> xz (bf16)
            gemm_bf16<0, 128, unsigned short><<<dim3(8, 128), thr, 0, stream>>>(
                xbf, 512, wb_in + (size_t)ed * 524288, xz, 1024,
                nullptr, nullptr, 512);
            conv_silu_k<<<dim3(kM * kDI / 1024), thr, 0, stream>>>(
                xz, xcb, conv_w + (size_t)ed * kDI * 4, conv_b + (size_t)ed * kDI, dir);
            // x-proj: (kM x 512) @ (64 x 512)^T -> dbl (f32)
            gemm_bf16<0, 64, float><<<dim3(1, 128), thr, 0, stream>>>(
                xcb, 512, wb_xp + (size_t)ed * 32768, dbl, 64,
                nullptr, nullptr, 512);
            // dt-proj (f32): (kM x 32, lda=64) @ (512 x 32)^T -> dtb, softplus
            gemm_f32<1, 128, 8><<<dim3(4, 128), thr, 0, stream>>>(
                dbl, 64, dt_w + (size_t)ed * 512 * 32, dtb, 512,
                dt_b + (size_t)ed * 512, nullptr, 32);
            // chunked scan
            scan_chunk<<<dim3(kB * kNC * 2), thr, 0, stream>>>(
                dtb, xcb, dbl, A_log + (size_t)ed * kDI * kDS, Sb, sdt, dir);
            scan_carry<<<dim3(kB * kDI / 256), thr, 0, stream>>>(
                Sb, sdt, A_log + (size_t)ed * kDI * kDS, h0b);
            scan_emit<<<dim3(kB * kNC * 2), thr, 0, stream>>>(
                dtb, xcb, dbl, A_log + (size_t)ed * kDI * kDS, h0b,
                Dp + (size_t)ed * kDI, xz, yb, dir);
            // out-proj accumulate into residual x (f32)
            gemm_bf16<2, 128, float><<<dim3(4, 128), thr, 0, stream>>>(
                yb, 512, wb_out + (size_t)ed * 262144, xcur, 512,
                nullptr, nullptr, 512);
        }
        // LN1 -> xn (f32) + xnbf (bf16)
        ln_k<<<dim3(kM), dim3(128), 0, stream>>>(
            xcur, ln1_g + e * kDM, ln1_b + e * kDM, xn, xnbf);
        // FFN1: gelu(xn @ w1^T + b1) -> Hb (bf16)
        gemm_bf16<3, 128, unsigned short><<<dim3(16, 128), thr, 0, stream>>>(
            xnbf, 512, wb_f1 + (size_t)e * 1048576, Hb, 2048,
            ff_b1 + (size_t)e * kDFF, nullptr, 512);
        // FFN2: Hb @ w2^T + b2 + xn -> t2 (f32)
        gemm_bf16<4, 128, float><<<dim3(4, 128), thr, 0, stream>>>(
            Hb, 2048, wb_f2 + (size_t)e * 1048576, t2, 512,
            ff_b2 + (size_t)e * kDM, xn, 2048);
        // LN2 -> x
        ln_k<<<dim3(kM), dim3(128), 0, stream>>>(
            t2, ln2_g + e * kDM, ln2_b + e * kDM, xcur, nullptr);
    }
    ln_k<<<dim3(kM), dim3(128), 0, stream>>>(xcur, lnf_g, lnf_b, xcur, nullptr);
}

// Round 4
// 1307.915 us; speedup vs baseline: 3.0248x; 1.0422x over previous
//
#include <hip/hip_runtime.h>
#include <hip/hip_bf16.h>
#include <math.h>

#define DEVI __device__ __forceinline__

namespace {
constexpr int kL   = 1024;
constexpr int kDM  = 512;
constexpr int kDS  = 16;
constexpr int kDFF = 2048;
constexpr int kR   = 32;
constexpr int kDI  = 512;
constexpr int kB   = 16;
constexpr int kM   = kB * kL;     // 16384 rows
constexpr int kNC  = 32;          // scan chunks
constexpr int kCH  = kL / kNC;    // 32 steps per chunk
}

typedef __attribute__((ext_vector_type(8))) short short8;
typedef __attribute__((ext_vector_type(4))) float f32x4;

DEVI float silu_f(float x)     { return x / (1.f + __expf(-x)); }
DEVI float softplus_f(float x) { return fmaxf(x, 0.f) + log1pf(__expf(-fabsf(x))); }
DEVI float gelu_f(float x)     { return 0.5f * x * (1.f + erff(x * 0.70710678118654752f)); }

DEVI unsigned short f2bf(float f) {
    unsigned int u = __float_as_uint(f);
    return (unsigned short)((u + 0x7fffu + ((u >> 16) & 1u)) >> 16);
}
DEVI float bf2f(unsigned short u) {
    return __uint_as_float(((unsigned int)u) << 16);
}
DEVI uint2 pack4(float4 v) {
    uint2 p;
    p.x = (unsigned int)f2bf(v.x) | ((unsigned int)f2bf(v.y) << 16);
    p.y = (unsigned int)f2bf(v.z) | ((unsigned int)f2bf(v.w) << 16);
    return p;
}

typedef const __attribute__((address_space(1))) unsigned int* gas1;
typedef __attribute__((address_space(3))) unsigned int* las3;
DEVI void gload16(const unsigned short* g, unsigned short* l) {
    __builtin_amdgcn_global_load_lds((gas1)g, (las3)l, 16, 0, 0);
}

// ---------------------------------------------------------------------------
// Merged one-shot weight conversion f32 -> bf16 (6 segments, dst contiguous
// in the same order as the segments).
// ---------------------------------------------------------------------------
struct WCvtArgs { const float* src[6]; unsigned int end[6]; };

__global__ __launch_bounds__(256) void cvt_weights_k(
    WCvtArgs a, unsigned short* __restrict__ dst)
{
    unsigned int i = (blockIdx.x * 256 + threadIdx.x) * 4;
    if (i >= a.end[5]) return;
    int j = 0;
    while (i >= a.end[j]) ++j;
    unsigned int base = j ? a.end[j - 1] : 0;
    float4 v = *(const float4*)&a.src[j][i - base];
    *(uint2*)&dst[i] = pack4(v);
}

// init: copy x f32 -> d_out and bf16 snapshot
__global__ __launch_bounds__(256) void init_x_k(
    const float* __restrict__ x, float* __restrict__ xo,
    unsigned short* __restrict__ xb)
{
    size_t i = (size_t)(blockIdx.x * 256 + threadIdx.x) * 4;
    float4 v = *(const float4*)&x[i];
    *(float4*)&xo[i] = v;
    *(uint2*)&xb[i] = pack4(v);
}

// ---------------------------------------------------------------------------
// bf16 MFMA GEMM. 128 x BN tile, BK=32, 4 waves (2x2), minimum 2-phase loop.
// LDS rows are 32 bf16 (64 B); reads XOR-swizzled (slot ^= (row>>1)&3) with
// the inverse swizzle applied to the global source address (rule 21).
// EPI: 0 plain (CT ushort/float), 1 bias+softplus (f32), 2 accumulate (f32),
//      3 bias+gelu (bf16), 4 bias+add (f32), 5 plain f32 + bf16 aux cols<32.
// ---------------------------------------------------------------------------
template <int EPI, int BN, typename CT>
__global__ __launch_bounds__(256) void gemm_bf16(
    const unsigned short* __restrict__ A, int lda,
    const unsigned short* __restrict__ W,
    CT* __restrict__ C, int ldc,
    const float* __restrict__ bias, const float* __restrict__ add,
    unsigned short* __restrict__ aux, int Kd)
{
    static_assert(BN == 64 || BN == 128, "");
    constexpr int NF = BN / 32;
    __shared__ alignas(16) unsigned short As[2][128 * 32];
    __shared__ alignas(16) unsigned short Ws[2][BN * 32];

    // XCD-aware swizzle (grid sizes here are multiples of 8)
    const int gx = gridDim.x;
    int flat = blockIdx.y * gx + blockIdx.x;
    const int total = gx * gridDim.y;
    if ((total & 7) == 0) {
        int q = total >> 3;
        flat = (flat & 7) * q + (flat >> 3);
    }
    const int bx = flat % gx;
    const int by = flat / gx;

    const int tid  = threadIdx.x;
    const int lane = tid & 63;
    const int wv   = tid >> 6;
    const int wm   = wv >> 1;
    const int wn   = wv & 1;
    const int row0 = by * 128;
    const int col0 = bx * BN;

    f32x4 acc[4][NF];
#pragma unroll
    for (int m = 0; m < 4; ++m)
#pragma unroll
        for (int n = 0; n < NF; ++n) acc[m][n] = (f32x4){0.f, 0.f, 0.f, 0.f};

    const int sr  = tid >> 2;                               // staging row 0..63
    const int scw = (((tid & 3) ^ ((tid >> 3) & 3)) * 8);   // pre-swizzled col
    const unsigned short* Ag = A + (size_t)(row0 + sr) * lda + scw;
    const unsigned short* Wg = W + (size_t)(col0 + sr) * Kd + scw;

    auto stage = [&](int buf, int k0) {
        gload16(Ag + k0, &As[buf][tid * 8]);
        gload16(Ag + (size_t)64 * lda + k0, &As[buf][2048 + tid * 8]);
        gload16(Wg + k0, &Ws[buf][tid * 8]);
        if (BN == 128)
            gload16(Wg + (size_t)64 * Kd + k0, &Ws[buf][2048 + tid * 8]);
    };

    const int nt = Kd / 32;
    stage(0, 0);
    __syncthreads();

    const int fr  = lane & 15;                                   // frag row/col
    const int sw8 = (((lane >> 4) ^ ((fr >> 1) & 3)) * 8);       // swizzled k-slot

    int cur = 0;
    for (int t = 0; t < nt; ++t) {
        if (t + 1 < nt) stage(cur ^ 1, (t + 1) * 32);
        short8 af[4], bf[NF];
#pragma unroll
        for (int m = 0; m < 4; ++m)
            af[m] = *(const short8*)&As[cur][(wm * 64 + m * 16 + fr) * 32 + sw8];
#pragma unroll
        for (int n = 0; n < NF; ++n)
            bf[n] = *(const short8*)&Ws[cur][(wn * (BN / 2) + n * 16 + fr) * 32 + sw8];
        __builtin_amdgcn_s_setprio(1);
#pragma unroll
        for (int m = 0; m < 4; ++m)
#pragma unroll
            for (int n = 0; n < NF; ++n)
                acc[m][n] = __builtin_amdgcn_mfma_f32_16x16x32_bf16(
                    af[m], bf[n], acc[m][n], 0, 0, 0);
        __builtin_amdgcn_s_setprio(0);
        __syncthreads();
        cur ^= 1;
    }

    const int cr = (lane >> 4) * 4;
#pragma unroll
    for (int m = 0; m < 4; ++m) {
#pragma unroll
        for (int n = 0; n < NF; ++n) {
            int cn = col0 + wn * (BN / 2) + n * 16 + fr;
#pragma unroll
            for (int r = 0; r < 4; ++r) {
                int rr = row0 + wm * 64 + m * 16 + cr + r;
                size_t idx = (size_t)rr * ldc + cn;
                float v = acc[m][n][r];
                if constexpr (EPI == 0) {
                    if constexpr (__is_same(CT, unsigned short)) C[idx] = f2bf(v);
                    else C[idx] = v;
                } else if constexpr (EPI == 1) {
                    C[idx] = softplus_f(v + bias[cn]);
                } else if constexpr (EPI == 2) {
                    C[idx] += v;
                } else if constexpr (EPI == 3) {
                    C[idx] = f2bf(gelu_f(v + bias[cn]));
                } else if constexpr (EPI == 4) {
                    C[idx] = v + bias[cn] + add[idx];
                } else {  // 5: f32 out + bf16 aux for cols < 32
                    C[idx] = v;
                    if (cn < 32) aux[(size_t)rr * 32 + cn] = f2bf(v);
                }
            }
        }
    }
}

// ---------------------------------------------------------------------------
// Depthwise causal/anti-causal conv (K=4) + bias + silu. bf16 in/out.
// xzd points at the dir's column block of xz2 (row stride 2048).
// ---------------------------------------------------------------------------
__global__ __launch_bounds__(256) void conv_silu_k(
    const unsigned short* __restrict__ xzd, unsigned short* __restrict__ xc,
    const float* __restrict__ w, const float* __restrict__ bias, int dir)
{
    int idx = blockIdx.x * 256 + threadIdx.x;     // kM*kDI/4 total
    if (idx >= kM * kDI / 4) return;
    int d0  = (idx & 127) * 4;
    int row = idx >> 7;
    int t   = row & (kL - 1);
    int b   = row >> 10;
    float acc[4];
#pragma unroll
    for (int j = 0; j < 4; ++j) acc[j] = bias[d0 + j];
#pragma unroll
    for (int k = 0; k < 4; ++k) {
        int tt = dir ? (t + 3 - k) : (t - 3 + k);
        if (tt >= 0 && tt < kL) {
            uint2 p = *(const uint2*)&xzd[(size_t)(b * kL + tt) * 2048 + d0];
            float xv[4] = {bf2f((unsigned short)(p.x & 0xffff)),
                           bf2f((unsigned short)(p.x >> 16)),
                           bf2f((unsigned short)(p.y & 0xffff)),
                           bf2f((unsigned short)(p.y >> 16))};
#pragma unroll
            for (int j = 0; j < 4; ++j)
                acc[j] = fmaf(w[(d0 + j) * 4 + k], xv[j], acc[j]);
        }
    }
    uint2 o;
    o.x = (unsigned int)f2bf(silu_f(acc[0])) | ((unsigned int)f2bf(silu_f(acc[1])) << 16);
    o.y = (unsigned int)f2bf(silu_f(acc[2])) | ((unsigned int)f2bf(silu_f(acc[3])) << 16);
    *(uint2*)&xc[(size_t)row * kDI + d0] = o;
}

// ---------------------------------------------------------------------------
// Chunked selective scan (f32 state; bf16 xc/z streams).
// ---------------------------------------------------------------------------
__global__ __launch_bounds__(256) void scan_chunk(
    const float* __restrict__ dtb, const unsigned short* __restrict__ xcb,
    const float* __restrict__ dbl, const float* __restrict__ A_log,
    float* __restrict__ S, float* __restrict__ sdt, int dir)
{
    int blk  = blockIdx.x;
    int dblk = blk & 1;
    int c    = (blk >> 1) & (kNC - 1);
    int b    = blk >> 6;
    int d    = dblk * 256 + threadIdx.x;

    const float* al = A_log + d * kDS;
    float A[16];
#pragma unroll
    for (int s = 0; s < 16; ++s) A[s] = -__expf(al[s]);

    float h[16];
#pragma unroll
    for (int s = 0; s < 16; ++s) h[s] = 0.f;
    float sum = 0.f;

    for (int i = 0; i < kCH; ++i) {
        int p   = c * kCH + i;
        int t   = dir ? (kL - 1 - p) : p;
        int row = b * kL + t;
        float dt = dtb[(size_t)row * kDI + d];
        float xv = bf2f(xcb[(size_t)row * kDI + d]);
        sum += dt;
        float dx = dt * xv;
        const float4* bp = (const float4*)(dbl + (size_t)row * 64 + kR);
        float4 b0 = bp[0], b1 = bp[1], b2 = bp[2], b3 = bp[3];
        float Bv[16] = {b0.x, b0.y, b0.z, b0.w, b1.x, b1.y, b1.z, b1.w,
                        b2.x, b2.y, b2.z, b2.w, b3.x, b3.y, b3.z, b3.w};
#pragma unroll
        for (int s = 0; s < 16; ++s) {
            float q = __expf(dt * A[s]);
            h[s] = fmaf(q, h[s], dx * Bv[s]);
        }
    }
    size_t base = (size_t)(b * kNC + c) * kDS * kDI + d;
#pragma unroll
    for (int s = 0; s < 16; ++s) S[base + s * kDI] = h[s];
    sdt[(size_t)(b * kNC + c) * kDI + d] = sum;
}

__global__ __launch_bounds__(256) void scan_carry(
    const float* __restrict__ S, const float* __restrict__ sdt,
    const float* __restrict__ A_log, float* __restrict__ h0)
{
    int g = blockIdx.x * 256 + threadIdx.x;
    int b = g >> 9;
    int d = g & (kDI - 1);
    const float* al = A_log + d * kDS;
    float A[16];
#pragma unroll
    for (int s = 0; s < 16; ++s) A[s] = -__expf(al[s]);
    float h[16];
#pragma unroll
    for (int s = 0; s < 16; ++s) h[s] = 0.f;

    for (int c = 0; c < kNC; ++c) {
        size_t base = (size_t)(b * kNC + c) * kDS * kDI + d;
        float sd = sdt[(size_t)(b * kNC + c) * kDI + d];
#pragma unroll
        for (int s = 0; s < 16; ++s) {
            h0[base + s * kDI] = h[s];
            float P = __expf(sd * A[s]);
            h[s] = fmaf(P, h[s], S[base + s * kDI]);
        }
    }
}

__global__ __launch_bounds__(256) void scan_emit(
    const float* __restrict__ dtb, const unsigned short* __restrict__ xcb,
    const float* __restrict__ dbl, const float* __restrict__ A_log,
    const float* __restrict__ h0v, const float* __restrict__ Dp,
    const unsigned short* __restrict__ zg, unsigned short* __restrict__ yb, int dir)
{
    int blk  = blockIdx.x;
    int dblk = blk & 1;
    int c    = (blk >> 1) & (kNC - 1);
    int b    = blk >> 6;
    int d    = dblk * 256 + threadIdx.x;

    const float* al = A_log + d * kDS;
    float A[16];
#pragma unroll
    for (int s = 0; s < 16; ++s) A[s] = -__expf(al[s]);
    float Dd = Dp[d];

    size_t hbase = (size_t)(b * kNC + c) * kDS * kDI + d;
    float h[16];
#pragma unroll
    for (int s = 0; s < 16; ++s) h[s] = h0v[hbase + s * kDI];

    for (int i = 0; i < kCH; ++i) {
        int p   = c * kCH + i;
        int t   = dir ? (kL - 1 - p) : p;
        int row = b * kL + t;
        float dt = dtb[(size_t)row * kDI + d];
        float xv = bf2f(xcb[(size_t)row * kDI + d]);
        float dx = dt * xv;
        const float4* bp = (const float4*)(dbl + (size_t)row * 64 + kR);
        float4 b0 = bp[0], b1 = bp[1], b2 = bp[2], b3 = bp[3];
        const float4* cp = (const float4*)(dbl + (size_t)row * 64 + kR + kDS);
        float4 c0 = cp[0], c1 = cp[1], c2 = cp[2], c3 = cp[3];
        float Bv[16] = {b0.x, b0.y, b0.z, b0.w, b1.x, b1.y, b1.z, b1.w,
                        b2.x, b2.y, b2.z, b2.w, b3.x, b3.y, b3.z, b3.w};
        float Cv[16] = {c0.x, c0.y, c0.z, c0.w, c1.x, c1.y, c1.z, c1.w,
                        c2.x, c2.y, c2.z, c2.w, c3.x, c3.y, c3.z, c3.w};
        float y = 0.f;
#pragma unroll
        for (int s = 0; s < 16; ++s) {
            float q = __expf(dt * A[s]);
            h[s] = fmaf(q, h[s], dx * Bv[s]);
            y = fmaf(h[s], Cv[s], y);
        }
        y += xv * Dd;
        float z = bf2f(zg[(size_t)row * 2048 + d]);
        yb[(size_t)row * kDI + d] = f2bf(y * silu_f(z));
    }
}

// ---------------------------------------------------------------------------
// LayerNorm over rows of 512. Optional second bf16 output.
// ---------------------------------------------------------------------------
__global__ __launch_bounds__(128) void ln_k(
    const float* __restrict__ in, const float* __restrict__ g,
    const float* __restrict__ bb, float* __restrict__ out,
    unsigned short* __restrict__ outbf)
{
    int row = blockIdx.x;
    int tid = threadIdx.x;
    float4 v = *(const float4*)&in[(size_t)row * kDM + tid * 4];
    float s1 = v.x + v.y + v.z + v.w;
    float s2 = v.x * v.x + v.y * v.y + v.z * v.z + v.w * v.w;
#pragma unroll
    for (int off = 32; off >= 1; off >>= 1) {
        s1 += __shfl_xor(s1, off);
        s2 += __shfl_xor(s2, off);
    }
    __shared__ float red[4];
    if ((tid & 63) == 0) { red[(tid >> 6) * 2] = s1; red[(tid >> 6) * 2 + 1] = s2; }
    __syncthreads();
    s1 = red[0] + red[2];
    s2 = red[1] + red[3];
    float mu  = s1 * (1.f / kDM);
    float var = s2 * (1.f / kDM) - mu * mu;
    float rs  = rsqrtf(var + 1e-5f);
    int cn = tid * 4;
    float4 gv = *(const float4*)&g[cn];
    float4 bv = *(const float4*)&bb[cn];
    float4 o;
    o.x = (v.x - mu) * rs * gv.x + bv.x;
    o.y = (v.y - mu) * rs * gv.y + bv.y;
    o.z = (v.z - mu) * rs * gv.z + bv.z;
    o.w = (v.w - mu) * rs * gv.w + bv.w;
    *(float4*)&out[(size_t)row * kDM + cn] = o;
    if (outbf)
        *(uint2*)&outbf[(size_t)row * kDM + cn] = pack4(o);
}

// ---------------------------------------------------------------------------
extern "C" void kernel_launch(void* const* d_in, const int* in_sizes, int n_in,
                              void* d_out, int out_size, void* d_ws, size_t ws_size,
                              hipStream_t stream)
{
    const float* x_in    = (const float*)d_in[0];
    const float* in_w    = (const float*)d_in[1];
    const float* conv_w  = (const float*)d_in[2];
    const float* conv_b  = (const float*)d_in[3];
    const float* xproj_w = (const float*)d_in[4];
    const float* dt_w    = (const float*)d_in[5];
    const float* dt_b    = (const float*)d_in[6];
    const float* A_log   = (const float*)d_in[7];
    const float* Dp      = (const float*)d_in[8];
    const float* out_w   = (const float*)d_in[9];
    const float* ff_w1   = (const float*)d_in[10];
    const float* ff_b1   = (const float*)d_in[11];
    const float* ff_w2   = (const float*)d_in[12];
    const float* ff_b2   = (const float*)d_in[13];
    const float* ln1_g   = (const float*)d_in[14];
    const float* ln1_b   = (const float*)d_in[15];
    const float* ln2_g   = (const float*)d_in[16];
    const float* ln2_b   = (const float*)d_in[17];
    const float* lnf_g   = (const float*)d_in[18];
    const float* lnf_b   = (const float*)d_in[19];

    float* ws = (float*)d_ws;
    unsigned short* wsb = (unsigned short*)d_ws;

    // bf16 weight region (bf16-element offsets), contiguous in cvt order
    unsigned short* wb_in  = wsb;                 // 2,097,152
    unsigned short* wb_xp  = wsb + 2097152;       //   131,072
    unsigned short* wb_out = wsb + 2228224;       // 1,048,576
    unsigned short* wb_f1  = wsb + 3276800;       // 2,097,152
    unsigned short* wb_f2  = wsb + 5373952;       // 2,097,152
    unsigned short* wb_dt  = wsb + 7471104;       //    65,536
    // arena base (f32 words)
    constexpr size_t A0 = 3768320;
    unsigned short* xbf  = (unsigned short*)(ws + A0);
    unsigned short* xz2  = (unsigned short*)(ws + A0 + 4194304);   // kM x 2048 bf16
    unsigned short* xcb  = (unsigned short*)(ws + A0 + 20971520);
    float*          dtb  = ws + A0 + 25165824;
    float*          dbl  = ws + A0 + 33554432;
    unsigned short* dtin = (unsigned short*)(ws + A0 + 34603008);  // kM x 32 bf16
    unsigned short* yb   = (unsigned short*)(ws + A0 + 34865152);
    float*          Sb   = ws + A0 + 39059456;
    float*          h0b  = ws + A0 + 43253760;
    float*          sdt  = ws + A0 + 47448064;
    // ffn-phase aliases (mamba arena dead by then)
    float*          xn   = ws + A0;                                // 8,388,608
    unsigned short* xnbf = (unsigned short*)(ws + A0 + 8388608);
    unsigned short* Hb   = (unsigned short*)(ws + A0 + 12582912);  // kM x 2048 bf16
    float*          t2   = ws + A0 + 29360128;

    float* xcur = (float*)d_out;

    dim3 thr(256);

    // one-time conversions + x init
    WCvtArgs wa;
    wa.src[0] = in_w;    wa.end[0] = 2097152;
    wa.src[1] = xproj_w; wa.end[1] = 2228224;
    wa.src[2] = out_w;   wa.end[2] = 3276800;
    wa.src[3] = ff_w1;   wa.end[3] = 5373952;
    wa.src[4] = ff_w2;   wa.end[4] = 7471104;
    wa.src[5] = dt_w;    wa.end[5] = 7536640;
    cvt_weights_k<<<dim3(7536640 / 1024), thr, 0, stream>>>(wa, wsb);
    init_x_k<<<dim3(8192), thr, 0, stream>>>(x_in, xcur, xbf);

    for (int e = 0; e < 2; ++e) {
        // fused dir0+dir1 in-proj: (kM x 512) @ (2048 x 512)^T -> xz2 (bf16)
        gemm_bf16<0, 128, unsigned short><<<dim3(16, 128), thr, 0, stream>>>(
            xbf, 512, wb_in + (size_t)e * 1048576, xz2, 2048,
            nullptr, nullptr, nullptr, 512);
        for (int dir = 0; dir < 2; ++dir) {
            int ed = e * 2 + dir;
            conv_silu_k<<<dim3(8192), thr, 0, stream>>>(
                xz2 + (size_t)dir * 1024, xcb,
                conv_w + (size_t)ed * 2048, conv_b + (size_t)ed * 512, dir);
            // x-proj -> dbl (f32) + dtin (bf16 cols 0..31)
            gemm_bf16<5, 64, float><<<dim3(1, 128), thr, 0, stream>>>(
                xcb, 512, wb_xp + (size_t)ed * 32768, dbl, 64,
                nullptr, nullptr, dtin, 512);
            // dt-proj: (kM x 32) @ (512 x 32)^T + bias -> softplus -> dtb (f32)
            gemm_bf16<1, 128, float><<<dim3(4, 128), thr, 0, stream>>>(
                dtin, 32, wb_dt + (size_t)ed * 16384, dtb, 512,
                dt_b + (size_t)ed * 512, nullptr, nullptr, 32);
            // chunked scan
            scan_chunk<<<dim3(kB * kNC * 2), thr, 0, stream>>>(
                dtb, xcb, dbl, A_log + (size_t)ed * 8192, Sb, sdt, dir);
            scan_carry<<<dim3(kB * kDI / 256), thr, 0, stream>>>(
                Sb, sdt, A_log + (size_t)ed * 8192, h0b);
            scan_emit<<<dim3(kB * kNC * 2), thr, 0, stream>>>(
                dtb, xcb, dbl, A_log + (size_t)ed * 8192, h0b,
                Dp + (size_t)ed * 512, xz2 + (size_t)dir * 1024 + 512, yb, dir);
            // out-proj accumulate into residual x (f32)
            gemm_bf16<2, 128, float><<<dim3(4, 128), thr, 0, stream>>>(
                yb, 512, wb_out + (size_t)ed * 262144, xcur, 512,
                nullptr, nullptr, nullptr, 512);
        }
        // LN1 -> xn (f32) + xnbf (bf16)
        ln_k<<<dim3(kM), dim3(128), 0, stream>>>(
            xcur, ln1_g + e * kDM, ln1_b + e * kDM, xn, xnbf);
        // FFN1: gelu(xn @ w1^T + b1) -> Hb (bf16)
        gemm_bf16<3, 128, unsigned short><<<dim3(16, 128), thr, 0, stream>>>(
            xnbf, 512, wb_f1 + (size_t)e * 1048576, Hb, 2048,
            ff_b1 + (size_t)e * kDFF, nullptr, nullptr, 512);
        // FFN2: Hb @ w2^T + b2 + xn -> t2 (f32)
        gemm_bf16<4, 128, float><<<dim3(4, 128), thr, 0, stream>>>(
            Hb, 2048, wb_f2 + (size_t)e * 1048576, t2, 512,
            ff_b2 + (size_t)e * kDM, xn, nullptr, 2048);
        // LN2 -> xcur (+ bf16 snapshot for next layer's in-proj)
        ln_k<<<dim3(kM), dim3(128), 0, stream>>>(
            t2, ln2_g + e * kDM, ln2_b + e * kDM, xcur,
            e == 0 ? xbf : nullptr);
    }
    ln_k<<<dim3(kM), dim3(128), 0, stream>>>(xcur, lnf_g, lnf_b, xcur, nullptr);
}

// Round 5
// 1241.191 us; speedup vs baseline: 3.1875x; 1.0538x over previous
//
#include <hip/hip_runtime.h>
#include <hip/hip_bf16.h>
#include <math.h>

#define DEVI __device__ __forceinline__

namespace {
constexpr int kL   = 1024;
constexpr int kDM  = 512;
constexpr int kDS  = 16;
constexpr int kDFF = 2048;
constexpr int kR   = 32;
constexpr int kDI  = 512;
constexpr int kB   = 16;
constexpr int kM   = kB * kL;     // 16384 rows
constexpr int kNC  = 32;          // scan chunks
constexpr int kCH  = kL / kNC;    // 32 steps per chunk
}

typedef __attribute__((ext_vector_type(8))) short short8;
typedef __attribute__((ext_vector_type(4))) float f32x4;

DEVI float silu_f(float x)     { return x / (1.f + __expf(-x)); }
DEVI float softplus_f(float x) { return fmaxf(x, 0.f) + log1pf(__expf(-fabsf(x))); }
DEVI float gelu_f(float x)     { return 0.5f * x * (1.f + erff(x * 0.70710678118654752f)); }

DEVI unsigned short f2bf(float f) {
    unsigned int u = __float_as_uint(f);
    return (unsigned short)((u + 0x7fffu + ((u >> 16) & 1u)) >> 16);
}
DEVI float bf2f(unsigned short u) {
    return __uint_as_float(((unsigned int)u) << 16);
}
DEVI uint2 pack4(float4 v) {
    uint2 p;
    p.x = (unsigned int)f2bf(v.x) | ((unsigned int)f2bf(v.y) << 16);
    p.y = (unsigned int)f2bf(v.z) | ((unsigned int)f2bf(v.w) << 16);
    return p;
}

typedef const __attribute__((address_space(1))) unsigned int* gas1;
typedef __attribute__((address_space(3))) unsigned int* las3;
DEVI void gload16(const unsigned short* g, unsigned short* l) {
    __builtin_amdgcn_global_load_lds((gas1)g, (las3)l, 16, 0, 0);
}

// ---------------------------------------------------------------------------
// One-shot weight conversion f32 -> bf16 (6 segments).
// ---------------------------------------------------------------------------
struct WCvtArgs { const float* src[6]; unsigned int end[6]; };

__global__ __launch_bounds__(256) void cvt_weights_k(
    WCvtArgs a, unsigned short* __restrict__ dst)
{
    unsigned int i = (blockIdx.x * 256 + threadIdx.x) * 4;
    if (i >= a.end[5]) return;
    int j = 0;
    while (i >= a.end[j]) ++j;
    unsigned int base = j ? a.end[j - 1] : 0;
    float4 v = *(const float4*)&a.src[j][i - base];
    *(uint2*)&dst[i] = pack4(v);
}

__global__ __launch_bounds__(256) void init_x_k(
    const float* __restrict__ x, float* __restrict__ xo,
    unsigned short* __restrict__ xb)
{
    size_t i = (size_t)(blockIdx.x * 256 + threadIdx.x) * 4;
    float4 v = *(const float4*)&x[i];
    *(float4*)&xo[i] = v;
    *(uint2*)&xb[i] = pack4(v);
}

// ---------------------------------------------------------------------------
// gemm8: BM x 256 tile, BK=64, 512 threads = 8 waves (2M x 4N), double-
// buffered LDS, counted-vmcnt pipeline (T3+T4), setprio (T5), XOR swizzle
// (T2 via pre-swizzled global source, rule 21). z-batched.
// EPI: 0 plain (CT), 3 bias+gelu (bf16), 4 bias+add (f32).
// ---------------------------------------------------------------------------
template <int BM, int EPI, typename CT>
__global__ __launch_bounds__(512, 2) void gemm8(
    const unsigned short* __restrict__ A, int lda, size_t zA,
    const unsigned short* __restrict__ W, size_t zW,
    CT* __restrict__ C, int ldc, size_t zC,
    const float* __restrict__ biasb, int zBias,
    const float* __restrict__ add, int Kd)
{
    static_assert(BM == 128 || BM == 256, "");
    constexpr int MF = BM / 32;            // m-frags per wave
    constexpr int AL = BM / 64;            // A gload16 per thread per tile
    __shared__ alignas(16) unsigned short As[2][BM * 64];
    __shared__ alignas(16) unsigned short Ws[2][256 * 64];

    const int z = blockIdx.z;
    A += (size_t)z * zA; W += (size_t)z * zW; C += (size_t)z * zC;
    const float* bias = biasb ? biasb + (size_t)z * zBias : nullptr;

    const int gx = gridDim.x;
    int flat = blockIdx.y * gx + blockIdx.x;
    const int total = gx * gridDim.y;
    if ((total & 7) == 0) { int q = total >> 3; flat = (flat & 7) * q + (flat >> 3); }
    const int bx = flat % gx;
    const int by = flat / gx;
    const int row0 = by * BM, col0 = bx * 256;

    const int tid = threadIdx.x, lane = tid & 63, wv = tid >> 6;
    const int wm = wv >> 2, wn = wv & 3;

    f32x4 acc[MF][4];
#pragma unroll
    for (int m = 0; m < MF; ++m)
#pragma unroll
        for (int n = 0; n < 4; ++n) acc[m][n] = (f32x4){0.f, 0.f, 0.f, 0.f};

    // staging: thread -> slot (tid&7), rows (tid>>3) + 64*i; source k-chunk
    // pre-swizzled so LDS[r][s] = global[r][s ^ (r&7)]
    const int srow = tid >> 3;
    const int sk   = (((tid & 7) ^ (srow & 7)) * 8);
    const unsigned short* Ag = A + (size_t)(row0 + srow) * lda + sk;
    const unsigned short* Wg = W + (size_t)(col0 + srow) * Kd + sk;
    const int ldso = srow * 64 + (tid & 7) * 8;    // = tid*8 elems (lane-linear)

    auto stage = [&](int buf, int k0) {
#pragma unroll
        for (int i = 0; i < AL; ++i)
            gload16(Ag + (size_t)(64 * i) * lda + k0, &As[buf][ldso + i * 4096]);
#pragma unroll
        for (int i = 0; i < 4; ++i)
            gload16(Wg + (size_t)(64 * i) * Kd + k0, &Ws[buf][ldso + i * 4096]);
    };

    const int nt = Kd / 64;
    stage(0, 0);
    if (nt > 1) stage(1, 64);

    const int fr = lane & 15;
    const int cb = lane >> 4;      // k-chunk (8 elems) within 32-elem half

    for (int t = 0; t < nt; ++t) {
        if (t + 1 < nt) {
            if constexpr (BM == 256) asm volatile("s_waitcnt vmcnt(8)" ::: "memory");
            else                     asm volatile("s_waitcnt vmcnt(6)" ::: "memory");
        } else {
            asm volatile("s_waitcnt vmcnt(0)" ::: "memory");
        }
        __builtin_amdgcn_s_barrier();
        __builtin_amdgcn_sched_barrier(0);

        const int cur = t & 1;
        __builtin_amdgcn_s_setprio(1);
#pragma unroll
        for (int kh = 0; kh < 2; ++kh) {
            short8 af[MF], bf[4];
#pragma unroll
            for (int m = 0; m < MF; ++m) {
                int r = wm * (BM / 2) + m * 16 + fr;
                af[m] = *(const short8*)
                    &As[cur][r * 64 + ((((kh << 2) | cb) ^ (r & 7)) << 3)];
            }
#pragma unroll
            for (int n = 0; n < 4; ++n) {
                int r = wn * 64 + n * 16 + fr;
                bf[n] = *(const short8*)
                    &Ws[cur][r * 64 + ((((kh << 2) | cb) ^ (r & 7)) << 3)];
            }
#pragma unroll
            for (int m = 0; m < MF; ++m)
#pragma unroll
                for (int n = 0; n < 4; ++n)
                    acc[m][n] = __builtin_amdgcn_mfma_f32_16x16x32_bf16(
                        af[m], bf[n], acc[m][n], 0, 0, 0);
        }
        __builtin_amdgcn_s_setprio(0);

        __builtin_amdgcn_sched_barrier(0);
        __builtin_amdgcn_s_barrier();
        __builtin_amdgcn_sched_barrier(0);
        if (t + 2 < nt) stage(cur, (t + 2) * 64);
    }

    const int cr = (lane >> 4) * 4;
#pragma unroll
    for (int m = 0; m < MF; ++m) {
#pragma unroll
        for (int n = 0; n < 4; ++n) {
            int cn = col0 + wn * 64 + n * 16 + fr;
#pragma unroll
            for (int r = 0; r < 4; ++r) {
                int rr = row0 + wm * (BM / 2) + m * 16 + cr + r;
                size_t idx = (size_t)rr * ldc + cn;
                float v = acc[m][n][r];
                if constexpr (EPI == 0) {
                    if constexpr (__is_same(CT, unsigned short)) C[idx] = f2bf(v);
                    else C[idx] = v;
                } else if constexpr (EPI == 3) {
                    C[idx] = f2bf(gelu_f(v + bias[cn]));
                } else {  // 4
                    C[idx] = v + bias[cn] + add[idx];
                }
            }
        }
    }
}

// ---------------------------------------------------------------------------
// Small 2-phase bf16 GEMM (x-proj, dt-proj). 128 x BN, BK=32, 4 waves.
// EPI: 1 bias+softplus (CT out), 5 plain f32 + bf16 aux cols<32. z-batched.
// ---------------------------------------------------------------------------
template <int EPI, int BN, typename CT>
__global__ __launch_bounds__(256) void gemm_bf16(
    const unsigned short* __restrict__ A, int lda, size_t zA,
    const unsigned short* __restrict__ W, size_t zW,
    CT* __restrict__ C, int ldc, size_t zC,
    const float* __restrict__ biasb, int zBias,
    unsigned short* __restrict__ auxb, size_t zAux, int Kd)
{
    static_assert(BN == 64 || BN == 128, "");
    constexpr int NF = BN / 32;
    __shared__ alignas(16) unsigned short As[2][128 * 32];
    __shared__ alignas(16) unsigned short Ws[2][BN * 32];

    const int z = blockIdx.z;
    A += (size_t)z * zA; W += (size_t)z * zW; C += (size_t)z * zC;
    const float* bias = biasb ? biasb + (size_t)z * zBias : nullptr;
    unsigned short* aux = auxb ? auxb + (size_t)z * zAux : nullptr;

    const int gx = gridDim.x;
    int flat = blockIdx.y * gx + blockIdx.x;
    const int total = gx * gridDim.y;
    if ((total & 7) == 0) {
        int q = total >> 3;
        flat = (flat & 7) * q + (flat >> 3);
    }
    const int bx = flat % gx;
    const int by = flat / gx;

    const int tid  = threadIdx.x;
    const int lane = tid & 63;
    const int wv   = tid >> 6;
    const int wm   = wv >> 1;
    const int wn   = wv & 1;
    const int row0 = by * 128;
    const int col0 = bx * BN;

    f32x4 acc[4][NF];
#pragma unroll
    for (int m = 0; m < 4; ++m)
#pragma unroll
        for (int n = 0; n < NF; ++n) acc[m][n] = (f32x4){0.f, 0.f, 0.f, 0.f};

    const int sr  = tid >> 2;
    const int scw = (((tid & 3) ^ ((tid >> 3) & 3)) * 8);
    const unsigned short* Ag = A + (size_t)(row0 + sr) * lda + scw;
    const unsigned short* Wg = W + (size_t)(col0 + sr) * Kd + scw;

    auto stage = [&](int buf, int k0) {
        gload16(Ag + k0, &As[buf][tid * 8]);
        gload16(Ag + (size_t)64 * lda + k0, &As[buf][2048 + tid * 8]);
        gload16(Wg + k0, &Ws[buf][tid * 8]);
        if (BN == 128)
            gload16(Wg + (size_t)64 * Kd + k0, &Ws[buf][2048 + tid * 8]);
    };

    const int nt = Kd / 32;
    stage(0, 0);
    __syncthreads();

    const int fr  = lane & 15;
    const int sw8 = (((lane >> 4) ^ ((fr >> 1) & 3)) * 8);

    int cur = 0;
    for (int t = 0; t < nt; ++t) {
        if (t + 1 < nt) stage(cur ^ 1, (t + 1) * 32);
        short8 af[4], bf[NF];
#pragma unroll
        for (int m = 0; m < 4; ++m)
            af[m] = *(const short8*)&As[cur][(wm * 64 + m * 16 + fr) * 32 + sw8];
#pragma unroll
        for (int n = 0; n < NF; ++n)
            bf[n] = *(const short8*)&Ws[cur][(wn * (BN / 2) + n * 16 + fr) * 32 + sw8];
        __builtin_amdgcn_s_setprio(1);
#pragma unroll
        for (int m = 0; m < 4; ++m)
#pragma unroll
            for (int n = 0; n < NF; ++n)
                acc[m][n] = __builtin_amdgcn_mfma_f32_16x16x32_bf16(
                    af[m], bf[n], acc[m][n], 0, 0, 0);
        __builtin_amdgcn_s_setprio(0);
        __syncthreads();
        cur ^= 1;
    }

    const int cr = (lane >> 4) * 4;
#pragma unroll
    for (int m = 0; m < 4; ++m) {
#pragma unroll
        for (int n = 0; n < NF; ++n) {
            int cn = col0 + wn * (BN / 2) + n * 16 + fr;
#pragma unroll
            for (int r = 0; r < 4; ++r) {
                int rr = row0 + wm * 64 + m * 16 + cr + r;
                size_t idx = (size_t)rr * ldc + cn;
                float v = acc[m][n][r];
                if constexpr (EPI == 1) {
                    float sp = softplus_f(v + bias[cn]);
                    if constexpr (__is_same(CT, unsigned short)) C[idx] = f2bf(sp);
                    else C[idx] = sp;
                } else {  // 5: f32 out + bf16 aux for cols < 32
                    C[idx] = v;
                    if (cn < 32) aux[(size_t)rr * 32 + cn] = f2bf(v);
                }
            }
        }
    }
}

// ---------------------------------------------------------------------------
// Depthwise conv (K=4) + bias + silu, both dirs (blockIdx.y = dir).
// ---------------------------------------------------------------------------
__global__ __launch_bounds__(256) void conv_silu_k(
    const unsigned short* __restrict__ xz2, unsigned short* __restrict__ xcb,
    const float* __restrict__ wb, const float* __restrict__ biasb)
{
    int dir = blockIdx.y;
    const unsigned short* xzd = xz2 + (size_t)dir * 1024;
    unsigned short* xc = xcb + (size_t)dir * kM * kDI;
    const float* w    = wb + (size_t)dir * 2048;
    const float* bias = biasb + (size_t)dir * 512;

    int idx = blockIdx.x * 256 + threadIdx.x;
    int d0  = (idx & 127) * 4;
    int row = idx >> 7;
    int t   = row & (kL - 1);
    int b   = row >> 10;
    float acc[4];
#pragma unroll
    for (int j = 0; j < 4; ++j) acc[j] = bias[d0 + j];
#pragma unroll
    for (int k = 0; k < 4; ++k) {
        int tt = dir ? (t + 3 - k) : (t - 3 + k);
        if (tt >= 0 && tt < kL) {
            uint2 p = *(const uint2*)&xzd[(size_t)(b * kL + tt) * 2048 + d0];
            float xv[4] = {bf2f((unsigned short)(p.x & 0xffff)),
                           bf2f((unsigned short)(p.x >> 16)),
                           bf2f((unsigned short)(p.y & 0xffff)),
                           bf2f((unsigned short)(p.y >> 16))};
#pragma unroll
            for (int j = 0; j < 4; ++j)
                acc[j] = fmaf(w[(d0 + j) * 4 + k], xv[j], acc[j]);
        }
    }
    uint2 o;
    o.x = (unsigned int)f2bf(silu_f(acc[0])) | ((unsigned int)f2bf(silu_f(acc[1])) << 16);
    o.y = (unsigned int)f2bf(silu_f(acc[2])) | ((unsigned int)f2bf(silu_f(acc[3])) << 16);
    *(uint2*)&xc[(size_t)row * kDI + d0] = o;
}

// ---------------------------------------------------------------------------
// Chunked selective scan, both dirs (blockIdx.y = dir). dt is bf16.
// ---------------------------------------------------------------------------
__global__ __launch_bounds__(256) void scan_chunk(
    const unsigned short* __restrict__ dtb2, const unsigned short* __restrict__ xcb2,
    const float* __restrict__ dbl2, const float* __restrict__ A_logb,
    float* __restrict__ S2, float* __restrict__ sdt2)
{
    int dir = blockIdx.y;
    const unsigned short* dtb = dtb2 + (size_t)dir * kM * kDI;
    const unsigned short* xcb = xcb2 + (size_t)dir * kM * kDI;
    const float* dbl = dbl2 + (size_t)dir * kM * 64;
    const float* A_log = A_logb + (size_t)dir * 8192;
    float* S   = S2 + (size_t)dir * (kB * kNC * kDS * kDI);
    float* sdt = sdt2 + (size_t)dir * (kB * kNC * kDI);

    int blk  = blockIdx.x;
    int dblk = blk & 1;
    int c    = (blk >> 1) & (kNC - 1);
    int b    = blk >> 6;
    int d    = dblk * 256 + threadIdx.x;

    const float* al = A_log + d * kDS;
    float A[16];
#pragma unroll
    for (int s = 0; s < 16; ++s) A[s] = -__expf(al[s]);

    float h[16];
#pragma unroll
    for (int s = 0; s < 16; ++s) h[s] = 0.f;
    float sum = 0.f;

    for (int i = 0; i < kCH; ++i) {
        int p   = c * kCH + i;
        int t   = dir ? (kL - 1 - p) : p;
        int row = b * kL + t;
        float dt = bf2f(dtb[(size_t)row * kDI + d]);
        float xv = bf2f(xcb[(size_t)row * kDI + d]);
        sum += dt;
        float dx = dt * xv;
        const float4* bp = (const float4*)(dbl + (size_t)row * 64 + kR);
        float4 b0 = bp[0], b1 = bp[1], b2 = bp[2], b3 = bp[3];
        float Bv[16] = {b0.x, b0.y, b0.z, b0.w, b1.x, b1.y, b1.z, b1.w,
                        b2.x, b2.y, b2.z, b2.w, b3.x, b3.y, b3.z, b3.w};
#pragma unroll
        for (int s = 0; s < 16; ++s) {
            float q = __expf(dt * A[s]);
            h[s] = fmaf(q, h[s], dx * Bv[s]);
        }
    }
    size_t base = (size_t)(b * kNC + c) * kDS * kDI + d;
#pragma unroll
    for (int s = 0; s < 16; ++s) S[base + s * kDI] = h[s];
    sdt[(size_t)(b * kNC + c) * kDI + d] = sum;
}

// carry scan; h0 written in-place over S
__global__ __launch_bounds__(256) void scan_carry(
    float* __restrict__ S2, const float* __restrict__ sdt2,
    const float* __restrict__ A_logb)
{
    int dir = blockIdx.y;
    float* S = S2 + (size_t)dir * (kB * kNC * kDS * kDI);
    const float* sdt = sdt2 + (size_t)dir * (kB * kNC * kDI);
    const float* A_log = A_logb + (size_t)dir * 8192;

    int g = blockIdx.x * 256 + threadIdx.x;
    int b = g >> 9;
    int d = g & (kDI - 1);
    const float* al = A_log + d * kDS;
    float A[16];
#pragma unroll
    for (int s = 0; s < 16; ++s) A[s] = -__expf(al[s]);
    float h[16];
#pragma unroll
    for (int s = 0; s < 16; ++s) h[s] = 0.f;

    for (int c = 0; c < kNC; ++c) {
        size_t base = (size_t)(b * kNC + c) * kDS * kDI + d;
        float sd = sdt[(size_t)(b * kNC + c) * kDI + d];
#pragma unroll
        for (int s = 0; s < 16; ++s) {
            float sv = S[base + s * kDI];
            S[base + s * kDI] = h[s];                 // h0 in-place
            float P = __expf(sd * A[s]);
            h[s] = fmaf(P, h[s], sv);
        }
    }
}

__global__ __launch_bounds__(256) void scan_emit(
    const unsigned short* __restrict__ dtb2, const unsigned short* __restrict__ xcb2,
    const float* __restrict__ dbl2, const float* __restrict__ A_logb,
    const float* __restrict__ h0v2, const float* __restrict__ Dpb,
    const unsigned short* __restrict__ xz2, unsigned short* __restrict__ yb2)
{
    int dir = blockIdx.y;
    const unsigned short* dtb = dtb2 + (size_t)dir * kM * kDI;
    const unsigned short* xcb = xcb2 + (size_t)dir * kM * kDI;
    const float* dbl = dbl2 + (size_t)dir * kM * 64;
    const float* A_log = A_logb + (size_t)dir * 8192;
    const float* h0v = h0v2 + (size_t)dir * (kB * kNC * kDS * kDI);
    const float* Dp = Dpb + (size_t)dir * 512;
    const unsigned short* zg = xz2 + (size_t)dir * 1024 + 512;
    unsigned short* yb = yb2 + (size_t)dir * kM * kDI;

    int blk  = blockIdx.x;
    int dblk = blk & 1;
    int c    = (blk >> 1) & (kNC - 1);
    int b    = blk >> 6;
    int d    = dblk * 256 + threadIdx.x;

    const float* al = A_log + d * kDS;
    float A[16];
#pragma unroll
    for (int s = 0; s < 16; ++s) A[s] = -__expf(al[s]);
    float Dd = Dp[d];

    size_t hbase = (size_t)(b * kNC + c) * kDS * kDI + d;
    float h[16];
#pragma unroll
    for (int s = 0; s < 16; ++s) h[s] = h0v[hbase + s * kDI];

    for (int i = 0; i < kCH; ++i) {
        int p   = c * kCH + i;
        int t   = dir ? (kL - 1 - p) : p;
        int row = b * kL + t;
        float dt = bf2f(dtb[(size_t)row * kDI + d]);
        float xv = bf2f(xcb[(size_t)row * kDI + d]);
        float dx = dt * xv;
        const float4* bp = (const float4*)(dbl + (size_t)row * 64 + kR);
        float4 b0 = bp[0], b1 = bp[1], b2 = bp[2], b3 = bp[3];
        const float4* cp = (const float4*)(dbl + (size_t)row * 64 + kR + kDS);
        float4 c0 = cp[0], c1 = cp[1], c2 = cp[2], c3 = cp[3];
        float Bv[16] = {b0.x, b0.y, b0.z, b0.w, b1.x, b1.y, b1.z, b1.w,
                        b2.x, b2.y, b2.z, b2.w, b3.x, b3.y, b3.z, b3.w};
        float Cv[16] = {c0.x, c0.y, c0.z, c0.w, c1.x, c1.y, c1.z, c1.w,
                        c2.x, c2.y, c2.z, c2.w, c3.x, c3.y, c3.z, c3.w};
        float y = 0.f;
#pragma unroll
        for (int s = 0; s < 16; ++s) {
            float q = __expf(dt * A[s]);
            h[s] = fmaf(q, h[s], dx * Bv[s]);
            y = fmaf(h[s], Cv[s], y);
        }
        y += xv * Dd;
        float z = bf2f(zg[(size_t)row * 2048 + d]);
        yb[(size_t)row * kDI + d] = f2bf(y * silu_f(z));
    }
}

// ---------------------------------------------------------------------------
// LayerNorm over rows of 512 with optional 2 add-inputs and bf16 copy.
// ---------------------------------------------------------------------------
__global__ __launch_bounds__(128) void ln_k(
    const float* __restrict__ in, const float* __restrict__ a0,
    const float* __restrict__ a1,
    const float* __restrict__ g, const float* __restrict__ bb,
    float* __restrict__ out, unsigned short* __restrict__ outbf)
{
    int row = blockIdx.x;
    int tid = threadIdx.x;
    size_t off = (size_t)row * kDM + tid * 4;
    float4 v = *(const float4*)&in[off];
    if (a0) {
        float4 u = *(const float4*)&a0[off];
        float4 w = *(const float4*)&a1[off];
        v.x += u.x + w.x; v.y += u.y + w.y; v.z += u.z + w.z; v.w += u.w + w.w;
    }
    float s1 = v.x + v.y + v.z + v.w;
    float s2 = v.x * v.x + v.y * v.y + v.z * v.z + v.w * v.w;
#pragma unroll
    for (int o = 32; o >= 1; o >>= 1) {
        s1 += __shfl_xor(s1, o);
        s2 += __shfl_xor(s2, o);
    }
    __shared__ float red[4];
    if ((tid & 63) == 0) { red[(tid >> 6) * 2] = s1; red[(tid >> 6) * 2 + 1] = s2; }
    __syncthreads();
    s1 = red[0] + red[2];
    s2 = red[1] + red[3];
    float mu  = s1 * (1.f / kDM);
    float var = s2 * (1.f / kDM) - mu * mu;
    float rs  = rsqrtf(var + 1e-5f);
    int cn = tid * 4;
    float4 gv = *(const float4*)&g[cn];
    float4 bv = *(const float4*)&bb[cn];
    float4 o;
    o.x = (v.x - mu) * rs * gv.x + bv.x;
    o.y = (v.y - mu) * rs * gv.y + bv.y;
    o.z = (v.z - mu) * rs * gv.z + bv.z;
    o.w = (v.w - mu) * rs * gv.w + bv.w;
    *(float4*)&out[off] = o;
    if (outbf)
        *(uint2*)&outbf[off] = pack4(o);
}

// ---------------------------------------------------------------------------
extern "C" void kernel_launch(void* const* d_in, const int* in_sizes, int n_in,
                              void* d_out, int out_size, void* d_ws, size_t ws_size,
                              hipStream_t stream)
{
    const float* x_in    = (const float*)d_in[0];
    const float* in_w    = (const float*)d_in[1];
    const float* conv_w  = (const float*)d_in[2];
    const float* conv_b  = (const float*)d_in[3];
    const float* xproj_w = (const float*)d_in[4];
    const float* dt_w    = (const float*)d_in[5];
    const float* dt_b    = (const float*)d_in[6];
    const float* A_log   = (const float*)d_in[7];
    const float* Dp      = (const float*)d_in[8];
    const float* out_w   = (const float*)d_in[9];
    const float* ff_w1   = (const float*)d_in[10];
    const float* ff_b1   = (const float*)d_in[11];
    const float* ff_w2   = (const float*)d_in[12];
    const float* ff_b2   = (const float*)d_in[13];
    const float* ln1_g   = (const float*)d_in[14];
    const float* ln1_b   = (const float*)d_in[15];
    const float* ln2_g   = (const float*)d_in[16];
    const float* ln2_b   = (const float*)d_in[17];
    const float* lnf_g   = (const float*)d_in[18];
    const float* lnf_b   = (const float*)d_in[19];

    float* ws = (float*)d_ws;
    unsigned short* wsb = (unsigned short*)d_ws;

    // bf16 weights (bf16-elem offsets into wsb)
    unsigned short* wb_in  = wsb;                 // in_w   [0, 2097152)
    unsigned short* wb_xp  = wsb + 2097152;       // xproj  [.., 2228224)
    unsigned short* wb_out = wsb + 2228224;       // out_w  [.., 3276800)
    unsigned short* wb_f1  = wsb + 3276800;       // ff_w1  [.., 5373952)
    unsigned short* wb_f2  = wsb + 5373952;       // ff_w2  [.., 7471104)
    unsigned short* wb_dt  = wsb + 7471104;       // dt_w   [.., 7536640)

    constexpr size_t A0 = 3768320;                // f32-word offset of arena
    unsigned short* xbf  = (unsigned short*)(ws + A0);                  // 4.19M w
    unsigned short* xz2  = (unsigned short*)(ws + A0 + 4194304);        // 16.78M w
    unsigned short* xcb2 = (unsigned short*)(ws + A0 + 20971520);       // 8.39M w
    unsigned short* yb2  = (unsigned short*)(ws + A0 + 29360128);       // 8.39M w
    float*          Sb2  = ws + A0 + 37748736;                          // 8.39M w (S/h0)
    unsigned short* dtb2 = (unsigned short*)(ws + A0 + 46137344);       // 8.39M w
    float*          dbl2 = ws + A0 + 54525952;                          // 2.10M w
    unsigned short* dtin2= (unsigned short*)(ws + A0 + 56623104);       // 0.52M w
    float*          sdt2 = ws + A0 + 57147392;                          // 0.52M w
    // out-proj outputs alias scan scratch (dead after scan_emit)
    float*          o2   = ws + A0 + 37748736;                          // 16.78M w
    // FFN-phase aliases (mamba arena dead)
    float*          xn   = ws + A0;                                     // 8.39M w
    unsigned short* xnbf = (unsigned short*)(ws + A0 + 8388608);        // 4.19M w
    unsigned short* Hb   = (unsigned short*)(ws + A0 + 12582912);       // 16.78M w
    float*          t2   = ws + A0 + 29360128;                          // 8.39M w

    float* xcur = (float*)d_out;
    dim3 thr(256);

    WCvtArgs wa;
    wa.src[0] = in_w;    wa.end[0] = 2097152;
    wa.src[1] = xproj_w; wa.end[1] = 2228224;
    wa.src[2] = out_w;   wa.end[2] = 3276800;
    wa.src[3] = ff_w1;   wa.end[3] = 5373952;
    wa.src[4] = ff_w2;   wa.end[4] = 7471104;
    wa.src[5] = dt_w;    wa.end[5] = 7536640;
    cvt_weights_k<<<dim3(7536640 / 1024), thr, 0, stream>>>(wa, wsb);
    init_x_k<<<dim3(8192), thr, 0, stream>>>(x_in, xcur, xbf);

    for (int e = 0; e < 2; ++e) {
        // in-proj (both dirs fused): (kM x 512) @ (2048 x 512)^T -> xz2 bf16
        gemm8<256, 0, unsigned short><<<dim3(8, 64, 1), dim3(512), 0, stream>>>(
            xbf, 512, 0, wb_in + (size_t)e * 1048576, 0, xz2, 2048, 0,
            nullptr, 0, nullptr, 512);
        // conv + silu (both dirs)
        conv_silu_k<<<dim3(8192, 2), thr, 0, stream>>>(
            xz2, xcb2, conv_w + (size_t)e * 4096, conv_b + (size_t)e * 1024);
        // x-proj (both dirs): -> dbl f32 + dtin bf16
        gemm_bf16<5, 64, float><<<dim3(1, 128, 2), thr, 0, stream>>>(
            xcb2, 512, (size_t)kM * 512, wb_xp + (size_t)e * 65536, 32768,
            dbl2, 64, (size_t)kM * 64, nullptr, 0, dtin2, (size_t)kM * 32, 512);
        // dt-proj (both dirs): softplus -> dtb bf16
        gemm_bf16<1, 128, unsigned short><<<dim3(4, 128, 2), thr, 0, stream>>>(
            dtin2, 32, (size_t)kM * 32, wb_dt + (size_t)e * 32768, 16384,
            dtb2, 512, (size_t)kM * 512, dt_b + (size_t)e * 1024, 512,
            nullptr, 0, 32);
        // scans (both dirs)
        scan_chunk<<<dim3(kB * kNC * 2, 2), thr, 0, stream>>>(
            dtb2, xcb2, dbl2, A_log + (size_t)e * 16384, Sb2, sdt2);
        scan_carry<<<dim3(kB * kDI / 256, 2), thr, 0, stream>>>(
            Sb2, sdt2, A_log + (size_t)e * 16384);
        scan_emit<<<dim3(kB * kNC * 2, 2), thr, 0, stream>>>(
            dtb2, xcb2, dbl2, A_log + (size_t)e * 16384, Sb2,
            Dp + (size_t)e * 1024, xz2, yb2);
        // out-proj (both dirs) -> o2 (separate buffers; LN1 adds)
        gemm8<128, 0, float><<<dim3(2, 128, 2), dim3(512), 0, stream>>>(
            yb2, 512, (size_t)kM * 512, wb_out + (size_t)e * 524288, 262144,
            o2, 512, (size_t)kM * 512, nullptr, 0, nullptr, 512);
        // LN1: normalize (xcur + o0 + o1) -> xn f32 + xnbf bf16
        ln_k<<<dim3(kM), dim3(128), 0, stream>>>(
            xcur, o2, o2 + (size_t)kM * 512,
            ln1_g + e * kDM, ln1_b + e * kDM, xn, xnbf);
        // FFN1: gelu(xn @ w1^T + b1) -> Hb bf16
        gemm8<256, 3, unsigned short><<<dim3(8, 64, 1), dim3(512), 0, stream>>>(
            xnbf, 512, 0, wb_f1 + (size_t)e * 1048576, 0, Hb, 2048, 0,
            ff_b1 + (size_t)e * kDFF, 0, nullptr, 512);
        // FFN2: Hb @ w2^T + b2 + xn -> t2 f32
        gemm8<128, 4, float><<<dim3(2, 128, 1), dim3(512), 0, stream>>>(
            Hb, 2048, 0, wb_f2 + (size_t)e * 1048576, 0, t2, 512, 0,
            ff_b2 + (size_t)e * kDM, 0, xn, 2048);
        // LN2 -> xcur (+ bf16 snapshot for next layer)
        ln_k<<<dim3(kM), dim3(128), 0, stream>>>(
            t2, nullptr, nullptr, ln2_g + e * kDM, ln2_b + e * kDM, xcur,
            e == 0 ? xbf : nullptr);
    }
    ln_k<<<dim3(kM), dim3(128), 0, stream>>>(
        xcur, nullptr, nullptr, lnf_g, lnf_b, xcur, nullptr);
}

// Round 6
// 1092.669 us; speedup vs baseline: 3.6207x; 1.1359x over previous
//
#include <hip/hip_runtime.h>
#include <hip/hip_bf16.h>
#include <math.h>

#define DEVI __device__ __forceinline__

namespace {
constexpr int kL   = 1024;
constexpr int kDM  = 512;
constexpr int kDS  = 16;
constexpr int kDFF = 2048;
constexpr int kR   = 32;
constexpr int kDI  = 512;
constexpr int kB   = 16;
constexpr int kM   = kB * kL;     // 16384 rows
constexpr int kNC  = 32;          // scan chunks
constexpr int kCH  = kL / kNC;    // 32 steps per chunk
}

typedef __attribute__((ext_vector_type(8))) short short8;
typedef __attribute__((ext_vector_type(4))) float f32x4;

DEVI float silu_f(float x)     { return x / (1.f + __expf(-x)); }
DEVI float softplus_f(float x) { return fmaxf(x, 0.f) + log1pf(__expf(-fabsf(x))); }
DEVI float gelu_f(float x)     { return 0.5f * x * (1.f + erff(x * 0.70710678118654752f)); }

DEVI unsigned short f2bf(float f) {
    unsigned int u = __float_as_uint(f);
    return (unsigned short)((u + 0x7fffu + ((u >> 16) & 1u)) >> 16);
}
DEVI float bf2f(unsigned short u) {
    return __uint_as_float(((unsigned int)u) << 16);
}
DEVI uint2 pack4(float4 v) {
    uint2 p;
    p.x = (unsigned int)f2bf(v.x) | ((unsigned int)f2bf(v.y) << 16);
    p.y = (unsigned int)f2bf(v.z) | ((unsigned int)f2bf(v.w) << 16);
    return p;
}

typedef const __attribute__((address_space(1))) unsigned int* gas1;
typedef __attribute__((address_space(3))) unsigned int* las3;
DEVI void gload16(const unsigned short* g, unsigned short* l) {
    __builtin_amdgcn_global_load_lds((gas1)g, (las3)l, 16, 0, 0);
}

// ---------------------------------------------------------------------------
// One-shot weight conversion f32 -> bf16 (6 segments).
// ---------------------------------------------------------------------------
struct WCvtArgs { const float* src[6]; unsigned int end[6]; };

__global__ __launch_bounds__(256) void cvt_weights_k(
    WCvtArgs a, unsigned short* __restrict__ dst)
{
    unsigned int i = (blockIdx.x * 256 + threadIdx.x) * 4;
    if (i >= a.end[5]) return;
    int j = 0;
    while (i >= a.end[j]) ++j;
    unsigned int base = j ? a.end[j - 1] : 0;
    float4 v = *(const float4*)&a.src[j][i - base];
    *(uint2*)&dst[i] = pack4(v);
}

__global__ __launch_bounds__(256) void init_x_k(
    const float* __restrict__ x, float* __restrict__ xo,
    unsigned short* __restrict__ xb)
{
    size_t i = (size_t)(blockIdx.x * 256 + threadIdx.x) * 4;
    float4 v = *(const float4*)&x[i];
    *(float4*)&xo[i] = v;
    *(uint2*)&xb[i] = pack4(v);
}

// ---------------------------------------------------------------------------
// gemm8: BM x 256 tile, BK=64, 512 threads = 8 waves (2M x 4N), double-
// buffered LDS, counted-vmcnt pipeline (T3+T4), setprio (T5), XOR swizzle
// (T2 via pre-swizzled global source, rule 21). z-batched.
// EPI: 0 plain (CT), 3 bias+gelu (bf16), 4 bias+add (f32).
// ---------------------------------------------------------------------------
template <int BM, int EPI, typename CT>
__global__ __launch_bounds__(512, 2) void gemm8(
    const unsigned short* __restrict__ A, int lda, size_t zA,
    const unsigned short* __restrict__ W, size_t zW,
    CT* __restrict__ C, int ldc, size_t zC,
    const float* __restrict__ biasb, int zBias,
    const float* __restrict__ add, int Kd)
{
    static_assert(BM == 128 || BM == 256, "");
    constexpr int MF = BM / 32;            // m-frags per wave
    constexpr int AL = BM / 64;            // A gload16 per thread per tile
    __shared__ alignas(16) unsigned short As[2][BM * 64];
    __shared__ alignas(16) unsigned short Ws[2][256 * 64];

    const int z = blockIdx.z;
    A += (size_t)z * zA; W += (size_t)z * zW; C += (size_t)z * zC;
    const float* bias = biasb ? biasb + (size_t)z * zBias : nullptr;

    const int gx = gridDim.x;
    int flat = blockIdx.y * gx + blockIdx.x;
    const int total = gx * gridDim.y;
    if ((total & 7) == 0) { int q = total >> 3; flat = (flat & 7) * q + (flat >> 3); }
    const int bx = flat % gx;
    const int by = flat / gx;
    const int row0 = by * BM, col0 = bx * 256;

    const int tid = threadIdx.x, lane = tid & 63, wv = tid >> 6;
    const int wm = wv >> 2, wn = wv & 3;

    f32x4 acc[MF][4];
#pragma unroll
    for (int m = 0; m < MF; ++m)
#pragma unroll
        for (int n = 0; n < 4; ++n) acc[m][n] = (f32x4){0.f, 0.f, 0.f, 0.f};

    // staging: thread -> slot (tid&7), rows (tid>>3) + 64*i; source k-chunk
    // pre-swizzled so LDS[r][s] = global[r][s ^ (r&7)]
    const int srow = tid >> 3;
    const int sk   = (((tid & 7) ^ (srow & 7)) * 8);
    const unsigned short* Ag = A + (size_t)(row0 + srow) * lda + sk;
    const unsigned short* Wg = W + (size_t)(col0 + srow) * Kd + sk;
    const int ldso = srow * 64 + (tid & 7) * 8;    // = tid*8 elems (lane-linear)

    auto stage = [&](int buf, int k0) {
#pragma unroll
        for (int i = 0; i < AL; ++i)
            gload16(Ag + (size_t)(64 * i) * lda + k0, &As[buf][ldso + i * 4096]);
#pragma unroll
        for (int i = 0; i < 4; ++i)
            gload16(Wg + (size_t)(64 * i) * Kd + k0, &Ws[buf][ldso + i * 4096]);
    };

    const int nt = Kd / 64;
    stage(0, 0);
    if (nt > 1) stage(1, 64);

    const int fr = lane & 15;
    const int cb = lane >> 4;      // k-chunk (8 elems) within 32-elem half

    for (int t = 0; t < nt; ++t) {
        if (t + 1 < nt) {
            if constexpr (BM == 256) asm volatile("s_waitcnt vmcnt(8)" ::: "memory");
            else                     asm volatile("s_waitcnt vmcnt(6)" ::: "memory");
        } else {
            asm volatile("s_waitcnt vmcnt(0)" ::: "memory");
        }
        __builtin_amdgcn_s_barrier();
        __builtin_amdgcn_sched_barrier(0);

        const int cur = t & 1;
        __builtin_amdgcn_s_setprio(1);
#pragma unroll
        for (int kh = 0; kh < 2; ++kh) {
            short8 af[MF], bf[4];
#pragma unroll
            for (int m = 0; m < MF; ++m) {
                int r = wm * (BM / 2) + m * 16 + fr;
                af[m] = *(const short8*)
                    &As[cur][r * 64 + ((((kh << 2) | cb) ^ (r & 7)) << 3)];
            }
#pragma unroll
            for (int n = 0; n < 4; ++n) {
                int r = wn * 64 + n * 16 + fr;
                bf[n] = *(const short8*)
                    &Ws[cur][r * 64 + ((((kh << 2) | cb) ^ (r & 7)) << 3)];
            }
#pragma unroll
            for (int m = 0; m < MF; ++m)
#pragma unroll
                for (int n = 0; n < 4; ++n)
                    acc[m][n] = __builtin_amdgcn_mfma_f32_16x16x32_bf16(
                        af[m], bf[n], acc[m][n], 0, 0, 0);
        }
        __builtin_amdgcn_s_setprio(0);

        __builtin_amdgcn_sched_barrier(0);
        __builtin_amdgcn_s_barrier();
        __builtin_amdgcn_sched_barrier(0);
        if (t + 2 < nt) stage(cur, (t + 2) * 64);
    }

    const int cr = (lane >> 4) * 4;
#pragma unroll
    for (int m = 0; m < MF; ++m) {
#pragma unroll
        for (int n = 0; n < 4; ++n) {
            int cn = col0 + wn * 64 + n * 16 + fr;
#pragma unroll
            for (int r = 0; r < 4; ++r) {
                int rr = row0 + wm * (BM / 2) + m * 16 + cr + r;
                size_t idx = (size_t)rr * ldc + cn;
                float v = acc[m][n][r];
                if constexpr (EPI == 0) {
                    if constexpr (__is_same(CT, unsigned short)) C[idx] = f2bf(v);
                    else C[idx] = v;
                } else if constexpr (EPI == 3) {
                    C[idx] = f2bf(gelu_f(v + bias[cn]));
                } else {  // 4
                    C[idx] = v + bias[cn] + add[idx];
                }
            }
        }
    }
}

// ---------------------------------------------------------------------------
// Small 2-phase bf16 GEMM (x-proj, dt-proj). 128 x BN, BK=32, 4 waves.
// EPI: 1 bias+softplus (CT out), 5 plain f32 + bf16 aux cols<32. z-batched.
// ---------------------------------------------------------------------------
template <int EPI, int BN, typename CT>
__global__ __launch_bounds__(256) void gemm_bf16(
    const unsigned short* __restrict__ A, int lda, size_t zA,
    const unsigned short* __restrict__ W, size_t zW,
    CT* __restrict__ C, int ldc, size_t zC,
    const float* __restrict__ biasb, int zBias,
    unsigned short* __restrict__ auxb, size_t zAux, int Kd)
{
    static_assert(BN == 64 || BN == 128, "");
    constexpr int NF = BN / 32;
    __shared__ alignas(16) unsigned short As[2][128 * 32];
    __shared__ alignas(16) unsigned short Ws[2][BN * 32];

    const int z = blockIdx.z;
    A += (size_t)z * zA; W += (size_t)z * zW; C += (size_t)z * zC;
    const float* bias = biasb ? biasb + (size_t)z * zBias : nullptr;
    unsigned short* aux = auxb ? auxb + (size_t)z * zAux : nullptr;

    const int gx = gridDim.x;
    int flat = blockIdx.y * gx + blockIdx.x;
    const int total = gx * gridDim.y;
    if ((total & 7) == 0) {
        int q = total >> 3;
        flat = (flat & 7) * q + (flat >> 3);
    }
    const int bx = flat % gx;
    const int by = flat / gx;

    const int tid  = threadIdx.x;
    const int lane = tid & 63;
    const int wv   = tid >> 6;
    const int wm   = wv >> 1;
    const int wn   = wv & 1;
    const int row0 = by * 128;
    const int col0 = bx * BN;

    f32x4 acc[4][NF];
#pragma unroll
    for (int m = 0; m < 4; ++m)
#pragma unroll
        for (int n = 0; n < NF; ++n) acc[m][n] = (f32x4){0.f, 0.f, 0.f, 0.f};

    const int sr  = tid >> 2;
    const int scw = (((tid & 3) ^ ((tid >> 3) & 3)) * 8);
    const unsigned short* Ag = A + (size_t)(row0 + sr) * lda + scw;
    const unsigned short* Wg = W + (size_t)(col0 + sr) * Kd + scw;

    auto stage = [&](int buf, int k0) {
        gload16(Ag + k0, &As[buf][tid * 8]);
        gload16(Ag + (size_t)64 * lda + k0, &As[buf][2048 + tid * 8]);
        gload16(Wg + k0, &Ws[buf][tid * 8]);
        if (BN == 128)
            gload16(Wg + (size_t)64 * Kd + k0, &Ws[buf][2048 + tid * 8]);
    };

    const int nt = Kd / 32;
    stage(0, 0);
    __syncthreads();

    const int fr  = lane & 15;
    const int sw8 = (((lane >> 4) ^ ((fr >> 1) & 3)) * 8);

    int cur = 0;
    for (int t = 0; t < nt; ++t) {
        if (t + 1 < nt) stage(cur ^ 1, (t + 1) * 32);
        short8 af[4], bf[NF];
#pragma unroll
        for (int m = 0; m < 4; ++m)
            af[m] = *(const short8*)&As[cur][(wm * 64 + m * 16 + fr) * 32 + sw8];
#pragma unroll
        for (int n = 0; n < NF; ++n)
            bf[n] = *(const short8*)&Ws[cur][(wn * (BN / 2) + n * 16 + fr) * 32 + sw8];
        __builtin_amdgcn_s_setprio(1);
#pragma unroll
        for (int m = 0; m < 4; ++m)
#pragma unroll
            for (int n = 0; n < NF; ++n)
                acc[m][n] = __builtin_amdgcn_mfma_f32_16x16x32_bf16(
                    af[m], bf[n], acc[m][n], 0, 0, 0);
        __builtin_amdgcn_s_setprio(0);
        __syncthreads();
        cur ^= 1;
    }

    const int cr = (lane >> 4) * 4;
#pragma unroll
    for (int m = 0; m < 4; ++m) {
#pragma unroll
        for (int n = 0; n < NF; ++n) {
            int cn = col0 + wn * (BN / 2) + n * 16 + fr;
#pragma unroll
            for (int r = 0; r < 4; ++r) {
                int rr = row0 + wm * 64 + m * 16 + cr + r;
                size_t idx = (size_t)rr * ldc + cn;
                float v = acc[m][n][r];
                if constexpr (EPI == 1) {
                    float sp = softplus_f(v + bias[cn]);
                    if constexpr (__is_same(CT, unsigned short)) C[idx] = f2bf(sp);
                    else C[idx] = sp;
                } else {  // 5: f32 out + bf16 aux for cols < 32
                    C[idx] = v;
                    if (cn < 32) aux[(size_t)rr * 32 + cn] = f2bf(v);
                }
            }
        }
    }
}

// ---------------------------------------------------------------------------
// Sliding-window depthwise conv (K=4) + bias + silu. Each thread: 8 channels
// x 32 t-steps, 3-row register window -> every xz element loaded exactly once
// (16 B loads), deep MLP. dir0: out[t]=sum w[k]*x[t-3+k]; dir1: out[t]=
// sum w[k]*x[t+3-k] == same window with reversed taps and 3-lag emission.
// 65536 tasks: task = dir<<15 | b<<11 | c<<6 | g.
// ---------------------------------------------------------------------------
__global__ __launch_bounds__(128) void conv_silu_k(
    const unsigned short* __restrict__ xz2, unsigned short* __restrict__ xcb,
    const float* __restrict__ wb, const float* __restrict__ biasb)
{
    const int task = blockIdx.x * 128 + threadIdx.x;
    const int g   = task & 63;
    const int c   = (task >> 6) & 31;
    const int b   = (task >> 11) & 15;
    const int dir = (task >> 15) & 1;
    const int d0  = g * 8;

    const unsigned short* xzd = xz2 + (size_t)dir * 1024 + (size_t)b * kL * 2048 + d0;
    unsigned short* xc = xcb + (size_t)dir * kM * kDI + (size_t)b * kL * kDI + d0;
    const float* w    = wb + (size_t)dir * 2048;
    const float* bias = biasb + (size_t)dir * 512;

    float wk[4][8];
#pragma unroll
    for (int k = 0; k < 4; ++k)
#pragma unroll
        for (int j = 0; j < 8; ++j)
            wk[k][j] = w[(d0 + j) * 4 + (dir ? 3 - k : k)];
    float bs[8];
#pragma unroll
    for (int j = 0; j < 8; ++j) bs[j] = bias[d0 + j];

    const int t0 = c * 32;
    const int rbase = dir ? t0 : t0 - 3;     // first window row

    auto loadrow = [&](int t, float* o) {
        if (t < 0 || t >= kL) {
#pragma unroll
            for (int j = 0; j < 8; ++j) o[j] = 0.f;
            return;
        }
        uint4 p = *(const uint4*)&xzd[(size_t)t * 2048];
        o[0] = bf2f((unsigned short)(p.x & 0xffff));
        o[1] = bf2f((unsigned short)(p.x >> 16));
        o[2] = bf2f((unsigned short)(p.y & 0xffff));
        o[3] = bf2f((unsigned short)(p.y >> 16));
        o[4] = bf2f((unsigned short)(p.z & 0xffff));
        o[5] = bf2f((unsigned short)(p.z >> 16));
        o[6] = bf2f((unsigned short)(p.w & 0xffff));
        o[7] = bf2f((unsigned short)(p.w >> 16));
    };

    float x0[8], x1[8], x2[8];
    loadrow(rbase + 0, x0);
    loadrow(rbase + 1, x1);
    loadrow(rbase + 2, x2);

#pragma unroll 4
    for (int i = 0; i < 32; ++i) {
        float x3[8];
        loadrow(rbase + 3 + i, x3);
        unsigned short o[8];
#pragma unroll
        for (int j = 0; j < 8; ++j) {
            float v = bs[j];
            v = fmaf(wk[0][j], x0[j], v);
            v = fmaf(wk[1][j], x1[j], v);
            v = fmaf(wk[2][j], x2[j], v);
            v = fmaf(wk[3][j], x3[j], v);
            o[j] = f2bf(silu_f(v));
        }
        *(uint4*)&xc[(size_t)(t0 + i) * kDI] = *(uint4*)o;
#pragma unroll
        for (int j = 0; j < 8; ++j) { x0[j] = x1[j]; x1[j] = x2[j]; x2[j] = x3[j]; }
    }
}

// ---------------------------------------------------------------------------
// Chunked selective scan, both dirs (blockIdx.y = dir). dt is bf16.
// ---------------------------------------------------------------------------
__global__ __launch_bounds__(256) void scan_chunk(
    const unsigned short* __restrict__ dtb2, const unsigned short* __restrict__ xcb2,
    const float* __restrict__ dbl2, const float* __restrict__ A_logb,
    float* __restrict__ S2, float* __restrict__ sdt2)
{
    int dir = blockIdx.y;
    const unsigned short* dtb = dtb2 + (size_t)dir * kM * kDI;
    const unsigned short* xcb = xcb2 + (size_t)dir * kM * kDI;
    const float* dbl = dbl2 + (size_t)dir * kM * 64;
    const float* A_log = A_logb + (size_t)dir * 8192;
    float* S   = S2 + (size_t)dir * (kB * kNC * kDS * kDI);
    float* sdt = sdt2 + (size_t)dir * (kB * kNC * kDI);

    int blk  = blockIdx.x;
    int dblk = blk & 1;
    int c    = (blk >> 1) & (kNC - 1);
    int b    = blk >> 6;
    int d    = dblk * 256 + threadIdx.x;

    const float* al = A_log + d * kDS;
    float A[16];
#pragma unroll
    for (int s = 0; s < 16; ++s) A[s] = -__expf(al[s]);

    float h[16];
#pragma unroll
    for (int s = 0; s < 16; ++s) h[s] = 0.f;
    float sum = 0.f;

#pragma unroll 2
    for (int i = 0; i < kCH; ++i) {
        int p   = c * kCH + i;
        int t   = dir ? (kL - 1 - p) : p;
        int row = b * kL + t;
        float dt = bf2f(dtb[(size_t)row * kDI + d]);
        float xv = bf2f(xcb[(size_t)row * kDI + d]);
        sum += dt;
        float dx = dt * xv;
        const float4* bp = (const float4*)(dbl + (size_t)row * 64 + kR);
        float4 b0 = bp[0], b1 = bp[1], b2 = bp[2], b3 = bp[3];
        float Bv[16] = {b0.x, b0.y, b0.z, b0.w, b1.x, b1.y, b1.z, b1.w,
                        b2.x, b2.y, b2.z, b2.w, b3.x, b3.y, b3.z, b3.w};
#pragma unroll
        for (int s = 0; s < 16; ++s) {
            float q = __expf(dt * A[s]);
            h[s] = fmaf(q, h[s], dx * Bv[s]);
        }
    }
    size_t base = (size_t)(b * kNC + c) * kDS * kDI + d;
#pragma unroll
    for (int s = 0; s < 16; ++s) S[base + s * kDI] = h[s];
    sdt[(size_t)(b * kNC + c) * kDI + d] = sum;
}

// carry scan; h0 written in-place over S
__global__ __launch_bounds__(256) void scan_carry(
    float* __restrict__ S2, const float* __restrict__ sdt2,
    const float* __restrict__ A_logb)
{
    int dir = blockIdx.y;
    float* S = S2 + (size_t)dir * (kB * kNC * kDS * kDI);
    const float* sdt = sdt2 + (size_t)dir * (kB * kNC * kDI);
    const float* A_log = A_logb + (size_t)dir * 8192;

    int g = blockIdx.x * 256 + threadIdx.x;
    int b = g >> 9;
    int d = g & (kDI - 1);
    const float* al = A_log + d * kDS;
    float A[16];
#pragma unroll
    for (int s = 0; s < 16; ++s) A[s] = -__expf(al[s]);
    float h[16];
#pragma unroll
    for (int s = 0; s < 16; ++s) h[s] = 0.f;

#pragma unroll 2
    for (int c = 0; c < kNC; ++c) {
        size_t base = (size_t)(b * kNC + c) * kDS * kDI + d;
        float sd = sdt[(size_t)(b * kNC + c) * kDI + d];
#pragma unroll
        for (int s = 0; s < 16; ++s) {
            float sv = S[base + s * kDI];
            S[base + s * kDI] = h[s];                 // h0 in-place
            float P = __expf(sd * A[s]);
            h[s] = fmaf(P, h[s], sv);
        }
    }
}

__global__ __launch_bounds__(256) void scan_emit(
    const unsigned short* __restrict__ dtb2, const unsigned short* __restrict__ xcb2,
    const float* __restrict__ dbl2, const float* __restrict__ A_logb,
    const float* __restrict__ h0v2, const float* __restrict__ Dpb,
    const unsigned short* __restrict__ xz2, unsigned short* __restrict__ yb2)
{
    int dir = blockIdx.y;
    const unsigned short* dtb = dtb2 + (size_t)dir * kM * kDI;
    const unsigned short* xcb = xcb2 + (size_t)dir * kM * kDI;
    const float* dbl = dbl2 + (size_t)dir * kM * 64;
    const float* A_log = A_logb + (size_t)dir * 8192;
    const float* h0v = h0v2 + (size_t)dir * (kB * kNC * kDS * kDI);
    const float* Dp = Dpb + (size_t)dir * 512;
    const unsigned short* zg = xz2 + (size_t)dir * 1024 + 512;
    unsigned short* yb = yb2 + (size_t)dir * kM * kDI;

    int blk  = blockIdx.x;
    int dblk = blk & 1;
    int c    = (blk >> 1) & (kNC - 1);
    int b    = blk >> 6;
    int d    = dblk * 256 + threadIdx.x;

    const float* al = A_log + d * kDS;
    float A[16];
#pragma unroll
    for (int s = 0; s < 16; ++s) A[s] = -__expf(al[s]);
    float Dd = Dp[d];

    size_t hbase = (size_t)(b * kNC + c) * kDS * kDI + d;
    float h[16];
#pragma unroll
    for (int s = 0; s < 16; ++s) h[s] = h0v[hbase + s * kDI];

#pragma unroll 2
    for (int i = 0; i < kCH; ++i) {
        int p   = c * kCH + i;
        int t   = dir ? (kL - 1 - p) : p;
        int row = b * kL + t;
        float dt = bf2f(dtb[(size_t)row * kDI + d]);
        float xv = bf2f(xcb[(size_t)row * kDI + d]);
        float dx = dt * xv;
        const float4* bp = (const float4*)(dbl + (size_t)row * 64 + kR);
        float4 b0 = bp[0], b1 = bp[1], b2 = bp[2], b3 = bp[3];
        const float4* cp = (const float4*)(dbl + (size_t)row * 64 + kR + kDS);
        float4 c0 = cp[0], c1 = cp[1], c2 = cp[2], c3 = cp[3];
        float Bv[16] = {b0.x, b0.y, b0.z, b0.w, b1.x, b1.y, b1.z, b1.w,
                        b2.x, b2.y, b2.z, b2.w, b3.x, b3.y, b3.z, b3.w};
        float Cv[16] = {c0.x, c0.y, c0.z, c0.w, c1.x, c1.y, c1.z, c1.w,
                        c2.x, c2.y, c2.z, c2.w, c3.x, c3.y, c3.z, c3.w};
        float y = 0.f;
#pragma unroll
        for (int s = 0; s < 16; ++s) {
            float q = __expf(dt * A[s]);
            h[s] = fmaf(q, h[s], dx * Bv[s]);
            y = fmaf(h[s], Cv[s], y);
        }
        y += xv * Dd;
        float z = bf2f(zg[(size_t)row * 2048 + d]);
        yb[(size_t)row * kDI + d] = f2bf(y * silu_f(z));
    }
}

// ---------------------------------------------------------------------------
// LayerNorm over rows of 512 with optional 2 add-inputs and bf16 copy.
// ---------------------------------------------------------------------------
__global__ __launch_bounds__(128) void ln_k(
    const float* __restrict__ in, const float* __restrict__ a0,
    const float* __restrict__ a1,
    const float* __restrict__ g, const float* __restrict__ bb,
    float* __restrict__ out, unsigned short* __restrict__ outbf)
{
    int row = blockIdx.x;
    int tid = threadIdx.x;
    size_t off = (size_t)row * kDM + tid * 4;
    float4 v = *(const float4*)&in[off];
    if (a0) {
        float4 u = *(const float4*)&a0[off];
        float4 w = *(const float4*)&a1[off];
        v.x += u.x + w.x; v.y += u.y + w.y; v.z += u.z + w.z; v.w += u.w + w.w;
    }
    float s1 = v.x + v.y + v.z + v.w;
    float s2 = v.x * v.x + v.y * v.y + v.z * v.z + v.w * v.w;
#pragma unroll
    for (int o = 32; o >= 1; o >>= 1) {
        s1 += __shfl_xor(s1, o);
        s2 += __shfl_xor(s2, o);
    }
    __shared__ float red[4];
    if ((tid & 63) == 0) { red[(tid >> 6) * 2] = s1; red[(tid >> 6) * 2 + 1] = s2; }
    __syncthreads();
    s1 = red[0] + red[2];
    s2 = red[1] + red[3];
    float mu  = s1 * (1.f / kDM);
    float var = s2 * (1.f / kDM) - mu * mu;
    float rs  = rsqrtf(var + 1e-5f);
    int cn = tid * 4;
    float4 gv = *(const float4*)&g[cn];
    float4 bv = *(const float4*)&bb[cn];
    float4 o;
    o.x = (v.x - mu) * rs * gv.x + bv.x;
    o.y = (v.y - mu) * rs * gv.y + bv.y;
    o.z = (v.z - mu) * rs * gv.z + bv.z;
    o.w = (v.w - mu) * rs * gv.w + bv.w;
    *(float4*)&out[off] = o;
    if (outbf)
        *(uint2*)&outbf[off] = pack4(o);
}

// ---------------------------------------------------------------------------
extern "C" void kernel_launch(void* const* d_in, const int* in_sizes, int n_in,
                              void* d_out, int out_size, void* d_ws, size_t ws_size,
                              hipStream_t stream)
{
    const float* x_in    = (const float*)d_in[0];
    const float* in_w    = (const float*)d_in[1];
    const float* conv_w  = (const float*)d_in[2];
    const float* conv_b  = (const float*)d_in[3];
    const float* xproj_w = (const float*)d_in[4];
    const float* dt_w    = (const float*)d_in[5];
    const float* dt_b    = (const float*)d_in[6];
    const float* A_log   = (const float*)d_in[7];
    const float* Dp      = (const float*)d_in[8];
    const float* out_w   = (const float*)d_in[9];
    const float* ff_w1   = (const float*)d_in[10];
    const float* ff_b1   = (const float*)d_in[11];
    const float* ff_w2   = (const float*)d_in[12];
    const float* ff_b2   = (const float*)d_in[13];
    const float* ln1_g   = (const float*)d_in[14];
    const float* ln1_b   = (const float*)d_in[15];
    const float* ln2_g   = (const float*)d_in[16];
    const float* ln2_b   = (const float*)d_in[17];
    const float* lnf_g   = (const float*)d_in[18];
    const float* lnf_b   = (const float*)d_in[19];

    float* ws = (float*)d_ws;
    unsigned short* wsb = (unsigned short*)d_ws;

    // bf16 weights (bf16-elem offsets into wsb)
    unsigned short* wb_in  = wsb;                 // in_w   [0, 2097152)
    unsigned short* wb_xp  = wsb + 2097152;       // xproj  [.., 2228224)
    unsigned short* wb_out = wsb + 2228224;       // out_w  [.., 3276800)
    unsigned short* wb_f1  = wsb + 3276800;       // ff_w1  [.., 5373952)
    unsigned short* wb_f2  = wsb + 5373952;       // ff_w2  [.., 7471104)
    unsigned short* wb_dt  = wsb + 7471104;       // dt_w   [.., 7536640)

    constexpr size_t A0 = 3768320;                // f32-word offset of arena
    unsigned short* xbf  = (unsigned short*)(ws + A0);                  // 4.19M w
    unsigned short* xz2  = (unsigned short*)(ws + A0 + 4194304);        // 16.78M w
    unsigned short* xcb2 = (unsigned short*)(ws + A0 + 20971520);       // 8.39M w
    unsigned short* yb2  = (unsigned short*)(ws + A0 + 29360128);       // 8.39M w
    float*          Sb2  = ws + A0 + 37748736;                          // 8.39M w (S/h0)
    unsigned short* dtb2 = (unsigned short*)(ws + A0 + 46137344);       // 8.39M w
    float*          dbl2 = ws + A0 + 54525952;                          // 2.10M w
    unsigned short* dtin2= (unsigned short*)(ws + A0 + 56623104);       // 0.52M w
    float*          sdt2 = ws + A0 + 57147392;                          // 0.52M w
    // out-proj outputs alias scan scratch (dead after scan_emit)
    float*          o2   = ws + A0 + 37748736;                          // 16.78M w
    // FFN-phase aliases (mamba arena dead)
    float*          xn   = ws + A0;                                     // 8.39M w
    unsigned short* xnbf = (unsigned short*)(ws + A0 + 8388608);        // 4.19M w
    unsigned short* Hb   = (unsigned short*)(ws + A0 + 12582912);       // 16.78M w
    float*          t2   = ws + A0 + 29360128;                          // 8.39M w

    float* xcur = (float*)d_out;
    dim3 thr(256);

    WCvtArgs wa;
    wa.src[0] = in_w;    wa.end[0] = 2097152;
    wa.src[1] = xproj_w; wa.end[1] = 2228224;
    wa.src[2] = out_w;   wa.end[2] = 3276800;
    wa.src[3] = ff_w1;   wa.end[3] = 5373952;
    wa.src[4] = ff_w2;   wa.end[4] = 7471104;
    wa.src[5] = dt_w;    wa.end[5] = 7536640;
    cvt_weights_k<<<dim3(7536640 / 1024), thr, 0, stream>>>(wa, wsb);
    init_x_k<<<dim3(8192), thr, 0, stream>>>(x_in, xcur, xbf);

    for (int e = 0; e < 2; ++e) {
        // in-proj (both dirs fused): (kM x 512) @ (2048 x 512)^T -> xz2 bf16
        gemm8<256, 0, unsigned short><<<dim3(8, 64, 1), dim3(512), 0, stream>>>(
            xbf, 512, 0, wb_in + (size_t)e * 1048576, 0, xz2, 2048, 0,
            nullptr, 0, nullptr, 512);
        // conv + silu (both dirs, sliding window)
        conv_silu_k<<<dim3(512), dim3(128), 0, stream>>>(
            xz2, xcb2, conv_w + (size_t)e * 4096, conv_b + (size_t)e * 1024);
        // x-proj (both dirs): -> dbl f32 + dtin bf16
        gemm_bf16<5, 64, float><<<dim3(1, 128, 2), thr, 0, stream>>>(
            xcb2, 512, (size_t)kM * 512, wb_xp + (size_t)e * 65536, 32768,
            dbl2, 64, (size_t)kM * 64, nullptr, 0, dtin2, (size_t)kM * 32, 512);
        // dt-proj (both dirs): softplus -> dtb bf16
        gemm_bf16<1, 128, unsigned short><<<dim3(4, 128, 2), thr, 0, stream>>>(
            dtin2, 32, (size_t)kM * 32, wb_dt + (size_t)e * 32768, 16384,
            dtb2, 512, (size_t)kM * 512, dt_b + (size_t)e * 1024, 512,
            nullptr, 0, 32);
        // scans (both dirs)
        scan_chunk<<<dim3(kB * kNC * 2, 2), thr, 0, stream>>>(
            dtb2, xcb2, dbl2, A_log + (size_t)e * 16384, Sb2, sdt2);
        scan_carry<<<dim3(kB * kDI / 256, 2), thr, 0, stream>>>(
            Sb2, sdt2, A_log + (size_t)e * 16384);
        scan_emit<<<dim3(kB * kNC * 2, 2), thr, 0, stream>>>(
            dtb2, xcb2, dbl2, A_log + (size_t)e * 16384, Sb2,
            Dp + (size_t)e * 1024, xz2, yb2);
        // out-proj (both dirs) -> o2 (separate buffers; LN1 adds)
        gemm8<128, 0, float><<<dim3(2, 128, 2), dim3(512), 0, stream>>>(
            yb2, 512, (size_t)kM * 512, wb_out + (size_t)e * 524288, 262144,
            o2, 512, (size_t)kM * 512, nullptr, 0, nullptr, 512);
        // LN1: normalize (xcur + o0 + o1) -> xn f32 + xnbf bf16
        ln_k<<<dim3(kM), dim3(128), 0, stream>>>(
            xcur, o2, o2 + (size_t)kM * 512,
            ln1_g + e * kDM, ln1_b + e * kDM, xn, xnbf);
        // FFN1: gelu(xn @ w1^T + b1) -> Hb bf16
        gemm8<256, 3, unsigned short><<<dim3(8, 64, 1), dim3(512), 0, stream>>>(
            xnbf, 512, 0, wb_f1 + (size_t)e * 1048576, 0, Hb, 2048, 0,
            ff_b1 + (size_t)e * kDFF, 0, nullptr, 512);
        // FFN2: Hb @ w2^T + b2 + xn -> t2 f32
        gemm8<128, 4, float><<<dim3(2, 128, 1), dim3(512), 0, stream>>>(
            Hb, 2048, 0, wb_f2 + (size_t)e * 1048576, 0, t2, 512, 0,
            ff_b2 + (size_t)e * kDM, 0, xn, 2048);
        // LN2 -> xcur (+ bf16 snapshot for next layer)
        ln_k<<<dim3(kM), dim3(128), 0, stream>>>(
            t2, nullptr, nullptr, ln2_g + e * kDM, ln2_b + e * kDM, xcur,
            e == 0 ? xbf : nullptr);
    }
    ln_k<<<dim3(kM), dim3(128), 0, stream>>>(
        xcur, nullptr, nullptr, lnf_g, lnf_b, xcur, nullptr);
}

// Round 7
// 971.521 us; speedup vs baseline: 4.0722x; 1.1247x over previous
//
#include <hip/hip_runtime.h>
#include <hip/hip_bf16.h>
#include <math.h>

#define DEVI __device__ __forceinline__

namespace {
constexpr int kL   = 1024;
constexpr int kDM  = 512;
constexpr int kDS  = 16;
constexpr int kDFF = 2048;
constexpr int kR   = 32;
constexpr int kDI  = 512;
constexpr int kB   = 16;
constexpr int kM   = kB * kL;     // 16384 rows
constexpr int kNC  = 32;          // scan chunks
constexpr int kCH  = kL / kNC;    // 32 steps per chunk
}

typedef __attribute__((ext_vector_type(8))) short short8;
typedef __attribute__((ext_vector_type(4))) float f32x4;

DEVI float silu_f(float x)     { return x / (1.f + __expf(-x)); }
DEVI float softplus_f(float x) { return fmaxf(x, 0.f) + log1pf(__expf(-fabsf(x))); }
DEVI float gelu_f(float x)     { return 0.5f * x * (1.f + erff(x * 0.70710678118654752f)); }

DEVI unsigned short f2bf(float f) {
    unsigned int u = __float_as_uint(f);
    return (unsigned short)((u + 0x7fffu + ((u >> 16) & 1u)) >> 16);
}
DEVI float bf2f(unsigned short u) {
    return __uint_as_float(((unsigned int)u) << 16);
}
DEVI uint2 pack4(float4 v) {
    uint2 p;
    p.x = (unsigned int)f2bf(v.x) | ((unsigned int)f2bf(v.y) << 16);
    p.y = (unsigned int)f2bf(v.z) | ((unsigned int)f2bf(v.w) << 16);
    return p;
}

typedef const __attribute__((address_space(1))) unsigned int* gas1;
typedef __attribute__((address_space(3))) unsigned int* las3;
DEVI void gload16(const unsigned short* g, unsigned short* l) {
    __builtin_amdgcn_global_load_lds((gas1)g, (las3)l, 16, 0, 0);
}

// ---------------------------------------------------------------------------
// One-shot weight conversion f32 -> bf16 (6 segments).
// ---------------------------------------------------------------------------
struct WCvtArgs { const float* src[6]; unsigned int end[6]; };

__global__ __launch_bounds__(256) void cvt_weights_k(
    WCvtArgs a, unsigned short* __restrict__ dst)
{
    unsigned int i = (blockIdx.x * 256 + threadIdx.x) * 4;
    if (i >= a.end[5]) return;
    int j = 0;
    while (i >= a.end[j]) ++j;
    unsigned int base = j ? a.end[j - 1] : 0;
    float4 v = *(const float4*)&a.src[j][i - base];
    *(uint2*)&dst[i] = pack4(v);
}

__global__ __launch_bounds__(256) void init_x_k(
    const float* __restrict__ x, float* __restrict__ xo,
    unsigned short* __restrict__ xb)
{
    size_t i = (size_t)(blockIdx.x * 256 + threadIdx.x) * 4;
    float4 v = *(const float4*)&x[i];
    *(float4*)&xo[i] = v;
    *(uint2*)&xb[i] = pack4(v);
}

// ---------------------------------------------------------------------------
// gemm8: BM x 256 tile, BK=64, 512 threads = 8 waves (2M x 4N), double-
// buffered LDS, counted-vmcnt pipeline (T3+T4), setprio (T5), XOR swizzle
// (T2 via pre-swizzled global source, rule 21). z-batched.
// EPI: 0 plain (CT), 3 bias+gelu (bf16), 4 bias+add (f32).
// ---------------------------------------------------------------------------
template <int BM, int EPI, typename CT>
__global__ __launch_bounds__(512, 2) void gemm8(
    const unsigned short* __restrict__ A, int lda, size_t zA,
    const unsigned short* __restrict__ W, size_t zW,
    CT* __restrict__ C, int ldc, size_t zC,
    const float* __restrict__ biasb, int zBias,
    const float* __restrict__ add, int Kd)
{
    static_assert(BM == 128 || BM == 256, "");
    constexpr int MF = BM / 32;            // m-frags per wave
    constexpr int AL = BM / 64;            // A gload16 per thread per tile
    __shared__ alignas(16) unsigned short As[2][BM * 64];
    __shared__ alignas(16) unsigned short Ws[2][256 * 64];

    const int z = blockIdx.z;
    A += (size_t)z * zA; W += (size_t)z * zW; C += (size_t)z * zC;
    const float* bias = biasb ? biasb + (size_t)z * zBias : nullptr;

    const int gx = gridDim.x;
    int flat = blockIdx.y * gx + blockIdx.x;
    const int total = gx * gridDim.y;
    if ((total & 7) == 0) { int q = total >> 3; flat = (flat & 7) * q + (flat >> 3); }
    const int bx = flat % gx;
    const int by = flat / gx;
    const int row0 = by * BM, col0 = bx * 256;

    const int tid = threadIdx.x, lane = tid & 63, wv = tid >> 6;
    const int wm = wv >> 2, wn = wv & 3;

    f32x4 acc[MF][4];
#pragma unroll
    for (int m = 0; m < MF; ++m)
#pragma unroll
        for (int n = 0; n < 4; ++n) acc[m][n] = (f32x4){0.f, 0.f, 0.f, 0.f};

    // staging: thread -> slot (tid&7), rows (tid>>3) + 64*i; source k-chunk
    // pre-swizzled so LDS[r][s] = global[r][s ^ (r&7)]
    const int srow = tid >> 3;
    const int sk   = (((tid & 7) ^ (srow & 7)) * 8);
    const unsigned short* Ag = A + (size_t)(row0 + srow) * lda + sk;
    const unsigned short* Wg = W + (size_t)(col0 + srow) * Kd + sk;
    const int ldso = srow * 64 + (tid & 7) * 8;    // = tid*8 elems (lane-linear)

    auto stage = [&](int buf, int k0) {
#pragma unroll
        for (int i = 0; i < AL; ++i)
            gload16(Ag + (size_t)(64 * i) * lda + k0, &As[buf][ldso + i * 4096]);
#pragma unroll
        for (int i = 0; i < 4; ++i)
            gload16(Wg + (size_t)(64 * i) * Kd + k0, &Ws[buf][ldso + i * 4096]);
    };

    const int nt = Kd / 64;
    stage(0, 0);
    if (nt > 1) stage(1, 64);

    const int fr = lane & 15;
    const int cb = lane >> 4;      // k-chunk (8 elems) within 32-elem half

    for (int t = 0; t < nt; ++t) {
        if (t + 1 < nt) {
            if constexpr (BM == 256) asm volatile("s_waitcnt vmcnt(8)" ::: "memory");
            else                     asm volatile("s_waitcnt vmcnt(6)" ::: "memory");
        } else {
            asm volatile("s_waitcnt vmcnt(0)" ::: "memory");
        }
        __builtin_amdgcn_s_barrier();
        __builtin_amdgcn_sched_barrier(0);

        const int cur = t & 1;
        __builtin_amdgcn_s_setprio(1);
#pragma unroll
        for (int kh = 0; kh < 2; ++kh) {
            short8 af[MF], bf[4];
#pragma unroll
            for (int m = 0; m < MF; ++m) {
                int r = wm * (BM / 2) + m * 16 + fr;
                af[m] = *(const short8*)
                    &As[cur][r * 64 + ((((kh << 2) | cb) ^ (r & 7)) << 3)];
            }
#pragma unroll
            for (int n = 0; n < 4; ++n) {
                int r = wn * 64 + n * 16 + fr;
                bf[n] = *(const short8*)
                    &Ws[cur][r * 64 + ((((kh << 2) | cb) ^ (r & 7)) << 3)];
            }
#pragma unroll
            for (int m = 0; m < MF; ++m)
#pragma unroll
                for (int n = 0; n < 4; ++n)
                    acc[m][n] = __builtin_amdgcn_mfma_f32_16x16x32_bf16(
                        af[m], bf[n], acc[m][n], 0, 0, 0);
        }
        __builtin_amdgcn_s_setprio(0);

        __builtin_amdgcn_sched_barrier(0);
        __builtin_amdgcn_s_barrier();
        __builtin_amdgcn_sched_barrier(0);
        if (t + 2 < nt) stage(cur, (t + 2) * 64);
    }

    const int cr = (lane >> 4) * 4;
#pragma unroll
    for (int m = 0; m < MF; ++m) {
#pragma unroll
        for (int n = 0; n < 4; ++n) {
            int cn = col0 + wn * 64 + n * 16 + fr;
#pragma unroll
            for (int r = 0; r < 4; ++r) {
                int rr = row0 + wm * (BM / 2) + m * 16 + cr + r;
                size_t idx = (size_t)rr * ldc + cn;
                float v = acc[m][n][r];
                if constexpr (EPI == 0) {
                    if constexpr (__is_same(CT, unsigned short)) C[idx] = f2bf(v);
                    else C[idx] = v;
                } else if constexpr (EPI == 3) {
                    C[idx] = f2bf(gelu_f(v + bias[cn]));
                } else {  // 4
                    C[idx] = v + bias[cn] + add[idx];
                }
            }
        }
    }
}

// ---------------------------------------------------------------------------
// Small 2-phase bf16 GEMM (x-proj, dt-proj). 128 x BN, BK=32, 4 waves.
// EPI: 1 bias+softplus (CT out), 5 plain f32 + bf16 aux cols<32. z-batched.
// ---------------------------------------------------------------------------
template <int EPI, int BN, typename CT>
__global__ __launch_bounds__(256) void gemm_bf16(
    const unsigned short* __restrict__ A, int lda, size_t zA,
    const unsigned short* __restrict__ W, size_t zW,
    CT* __restrict__ C, int ldc, size_t zC,
    const float* __restrict__ biasb, int zBias,
    unsigned short* __restrict__ auxb, size_t zAux, int Kd)
{
    static_assert(BN == 64 || BN == 128, "");
    constexpr int NF = BN / 32;
    __shared__ alignas(16) unsigned short As[2][128 * 32];
    __shared__ alignas(16) unsigned short Ws[2][BN * 32];

    const int z = blockIdx.z;
    A += (size_t)z * zA; W += (size_t)z * zW; C += (size_t)z * zC;
    const float* bias = biasb ? biasb + (size_t)z * zBias : nullptr;
    unsigned short* aux = auxb ? auxb + (size_t)z * zAux : nullptr;

    const int gx = gridDim.x;
    int flat = blockIdx.y * gx + blockIdx.x;
    const int total = gx * gridDim.y;
    if ((total & 7) == 0) {
        int q = total >> 3;
        flat = (flat & 7) * q + (flat >> 3);
    }
    const int bx = flat % gx;
    const int by = flat / gx;

    const int tid  = threadIdx.x;
    const int lane = tid & 63;
    const int wv   = tid >> 6;
    const int wm   = wv >> 1;
    const int wn   = wv & 1;
    const int row0 = by * 128;
    const int col0 = bx * BN;

    f32x4 acc[4][NF];
#pragma unroll
    for (int m = 0; m < 4; ++m)
#pragma unroll
        for (int n = 0; n < NF; ++n) acc[m][n] = (f32x4){0.f, 0.f, 0.f, 0.f};

    const int sr  = tid >> 2;
    const int scw = (((tid & 3) ^ ((tid >> 3) & 3)) * 8);
    const unsigned short* Ag = A + (size_t)(row0 + sr) * lda + scw;
    const unsigned short* Wg = W + (size_t)(col0 + sr) * Kd + scw;

    auto stage = [&](int buf, int k0) {
        gload16(Ag + k0, &As[buf][tid * 8]);
        gload16(Ag + (size_t)64 * lda + k0, &As[buf][2048 + tid * 8]);
        gload16(Wg + k0, &Ws[buf][tid * 8]);
        if (BN == 128)
            gload16(Wg + (size_t)64 * Kd + k0, &Ws[buf][2048 + tid * 8]);
    };

    const int nt = Kd / 32;
    stage(0, 0);
    __syncthreads();

    const int fr  = lane & 15;
    const int sw8 = (((lane >> 4) ^ ((fr >> 1) & 3)) * 8);

    int cur = 0;
    for (int t = 0; t < nt; ++t) {
        if (t + 1 < nt) stage(cur ^ 1, (t + 1) * 32);
        short8 af[4], bf[NF];
#pragma unroll
        for (int m = 0; m < 4; ++m)
            af[m] = *(const short8*)&As[cur][(wm * 64 + m * 16 + fr) * 32 + sw8];
#pragma unroll
        for (int n = 0; n < NF; ++n)
            bf[n] = *(const short8*)&Ws[cur][(wn * (BN / 2) + n * 16 + fr) * 32 + sw8];
        __builtin_amdgcn_s_setprio(1);
#pragma unroll
        for (int m = 0; m < 4; ++m)
#pragma unroll
            for (int n = 0; n < NF; ++n)
                acc[m][n] = __builtin_amdgcn_mfma_f32_16x16x32_bf16(
                    af[m], bf[n], acc[m][n], 0, 0, 0);
        __builtin_amdgcn_s_setprio(0);
        __syncthreads();
        cur ^= 1;
    }

    const int cr = (lane >> 4) * 4;
#pragma unroll
    for (int m = 0; m < 4; ++m) {
#pragma unroll
        for (int n = 0; n < NF; ++n) {
            int cn = col0 + wn * (BN / 2) + n * 16 + fr;
#pragma unroll
            for (int r = 0; r < 4; ++r) {
                int rr = row0 + wm * 64 + m * 16 + cr + r;
                size_t idx = (size_t)rr * ldc + cn;
                float v = acc[m][n][r];
                if constexpr (EPI == 1) {
                    float sp = softplus_f(v + bias[cn]);
                    if constexpr (__is_same(CT, unsigned short)) C[idx] = f2bf(sp);
                    else C[idx] = sp;
                } else {  // 5: f32 out + bf16 aux for cols < 32
                    C[idx] = v;
                    if (cn < 32) aux[(size_t)rr * 32 + cn] = f2bf(v);
                }
            }
        }
    }
}

// ---------------------------------------------------------------------------
// Sliding-window depthwise conv (K=4) + bias + silu. Each thread: 8 channels
// x 32 t-steps, 3-row register window -> every xz element loaded exactly once.
// ---------------------------------------------------------------------------
__global__ __launch_bounds__(128) void conv_silu_k(
    const unsigned short* __restrict__ xz2, unsigned short* __restrict__ xcb,
    const float* __restrict__ wb, const float* __restrict__ biasb)
{
    const int task = blockIdx.x * 128 + threadIdx.x;
    const int g   = task & 63;
    const int c   = (task >> 6) & 31;
    const int b   = (task >> 11) & 15;
    const int dir = (task >> 15) & 1;
    const int d0  = g * 8;

    const unsigned short* xzd = xz2 + (size_t)dir * 1024 + (size_t)b * kL * 2048 + d0;
    unsigned short* xc = xcb + (size_t)dir * kM * kDI + (size_t)b * kL * kDI + d0;
    const float* w    = wb + (size_t)dir * 2048;
    const float* bias = biasb + (size_t)dir * 512;

    float wk[4][8];
#pragma unroll
    for (int k = 0; k < 4; ++k)
#pragma unroll
        for (int j = 0; j < 8; ++j)
            wk[k][j] = w[(d0 + j) * 4 + (dir ? 3 - k : k)];
    float bs[8];
#pragma unroll
    for (int j = 0; j < 8; ++j) bs[j] = bias[d0 + j];

    const int t0 = c * 32;
    const int rbase = dir ? t0 : t0 - 3;     // first window row

    auto loadrow = [&](int t, float* o) {
        if (t < 0 || t >= kL) {
#pragma unroll
            for (int j = 0; j < 8; ++j) o[j] = 0.f;
            return;
        }
        uint4 p = *(const uint4*)&xzd[(size_t)t * 2048];
        o[0] = bf2f((unsigned short)(p.x & 0xffff));
        o[1] = bf2f((unsigned short)(p.x >> 16));
        o[2] = bf2f((unsigned short)(p.y & 0xffff));
        o[3] = bf2f((unsigned short)(p.y >> 16));
        o[4] = bf2f((unsigned short)(p.z & 0xffff));
        o[5] = bf2f((unsigned short)(p.z >> 16));
        o[6] = bf2f((unsigned short)(p.w & 0xffff));
        o[7] = bf2f((unsigned short)(p.w >> 16));
    };

    float x0[8], x1[8], x2[8];
    loadrow(rbase + 0, x0);
    loadrow(rbase + 1, x1);
    loadrow(rbase + 2, x2);

#pragma unroll 4
    for (int i = 0; i < 32; ++i) {
        float x3[8];
        loadrow(rbase + 3 + i, x3);
        unsigned short o[8];
#pragma unroll
        for (int j = 0; j < 8; ++j) {
            float v = bs[j];
            v = fmaf(wk[0][j], x0[j], v);
            v = fmaf(wk[1][j], x1[j], v);
            v = fmaf(wk[2][j], x2[j], v);
            v = fmaf(wk[3][j], x3[j], v);
            o[j] = f2bf(silu_f(v));
        }
        *(uint4*)&xc[(size_t)(t0 + i) * kDI] = *(uint4*)o;
#pragma unroll
        for (int j = 0; j < 8; ++j) { x0[j] = x1[j]; x1[j] = x2[j]; x2[j] = x3[j]; }
    }
}

// ---------------------------------------------------------------------------
// Chunked selective scan, both dirs (blockIdx.y = dir). dt is bf16.
// ---------------------------------------------------------------------------
__global__ __launch_bounds__(256) void scan_chunk(
    const unsigned short* __restrict__ dtb2, const unsigned short* __restrict__ xcb2,
    const float* __restrict__ dbl2, const float* __restrict__ A_logb,
    float* __restrict__ S2, float* __restrict__ sdt2)
{
    int dir = blockIdx.y;
    const unsigned short* dtb = dtb2 + (size_t)dir * kM * kDI;
    const unsigned short* xcb = xcb2 + (size_t)dir * kM * kDI;
    const float* dbl = dbl2 + (size_t)dir * kM * 64;
    const float* A_log = A_logb + (size_t)dir * 8192;
    float* S   = S2 + (size_t)dir * (kB * kNC * kDS * kDI);
    float* sdt = sdt2 + (size_t)dir * (kB * kNC * kDI);

    int blk  = blockIdx.x;
    int dblk = blk & 1;
    int c    = (blk >> 1) & (kNC - 1);
    int b    = blk >> 6;
    int d    = dblk * 256 + threadIdx.x;

    const float* al = A_log + d * kDS;
    float A[16];
#pragma unroll
    for (int s = 0; s < 16; ++s) A[s] = -__expf(al[s]);

    float h[16];
#pragma unroll
    for (int s = 0; s < 16; ++s) h[s] = 0.f;
    float sum = 0.f;

#pragma unroll 2
    for (int i = 0; i < kCH; ++i) {
        int p   = c * kCH + i;
        int t   = dir ? (kL - 1 - p) : p;
        int row = b * kL + t;
        float dt = bf2f(dtb[(size_t)row * kDI + d]);
        float xv = bf2f(xcb[(size_t)row * kDI + d]);
        sum += dt;
        float dx = dt * xv;
        const float4* bp = (const float4*)(dbl + (size_t)row * 64 + kR);
        float4 b0 = bp[0], b1 = bp[1], b2 = bp[2], b3 = bp[3];
        float Bv[16] = {b0.x, b0.y, b0.z, b0.w, b1.x, b1.y, b1.z, b1.w,
                        b2.x, b2.y, b2.z, b2.w, b3.x, b3.y, b3.z, b3.w};
#pragma unroll
        for (int s = 0; s < 16; ++s) {
            float q = __expf(dt * A[s]);
            h[s] = fmaf(q, h[s], dx * Bv[s]);
        }
    }
    size_t base = (size_t)(b * kNC + c) * kDS * kDI + d;
#pragma unroll
    for (int s = 0; s < 16; ++s) S[base + s * kDI] = h[s];
    sdt[(size_t)(b * kNC + c) * kDI + d] = sum;
}

// ---------------------------------------------------------------------------
// Carry scan: one thread per (b,d,s) recurrence; h0 written in-place over S.
// 131072 threads/dir, fully unrolled 32-step chain, coalesced over d.
// ---------------------------------------------------------------------------
__global__ __launch_bounds__(256) void scan_carry(
    float* __restrict__ S2, const float* __restrict__ sdt2,
    const float* __restrict__ A_logb)
{
    int dir = blockIdx.y;
    float* S = S2 + (size_t)dir * (kB * kNC * kDS * kDI);
    const float* sdt = sdt2 + (size_t)dir * (kB * kNC * kDI);
    const float* A_log = A_logb + (size_t)dir * 8192;

    int g = blockIdx.x * 256 + threadIdx.x;   // 0..131071
    int d = g & (kDI - 1);
    int s = (g >> 9) & 15;
    int b = g >> 13;

    float A = -__expf(A_log[d * kDS + s]);
    float h = 0.f;
#pragma unroll
    for (int c = 0; c < kNC; ++c) {
        size_t base = ((size_t)(b * kNC + c) * kDS + s) * kDI + d;
        float sv = S[base];
        float sd = sdt[(size_t)(b * kNC + c) * kDI + d];
        S[base] = h;                          // h0 in-place
        h = fmaf(__expf(sd * A), h, sv);
    }
}

__global__ __launch_bounds__(256) void scan_emit(
    const unsigned short* __restrict__ dtb2, const unsigned short* __restrict__ xcb2,
    const float* __restrict__ dbl2, const float* __restrict__ A_logb,
    const float* __restrict__ h0v2, const float* __restrict__ Dpb,
    const unsigned short* __restrict__ xz2, unsigned short* __restrict__ yb2)
{
    int dir = blockIdx.y;
    const unsigned short* dtb = dtb2 + (size_t)dir * kM * kDI;
    const unsigned short* xcb = xcb2 + (size_t)dir * kM * kDI;
    const float* dbl = dbl2 + (size_t)dir * kM * 64;
    const float* A_log = A_logb + (size_t)dir * 8192;
    const float* h0v = h0v2 + (size_t)dir * (kB * kNC * kDS * kDI);
    const float* Dp = Dpb + (size_t)dir * 512;
    const unsigned short* zg = xz2 + (size_t)dir * 1024 + 512;
    unsigned short* yb = yb2 + (size_t)dir * kM * kDI;

    int blk  = blockIdx.x;
    int dblk = blk & 1;
    int c    = (blk >> 1) & (kNC - 1);
    int b    = blk >> 6;
    int d    = dblk * 256 + threadIdx.x;

    const float* al = A_log + d * kDS;
    float A[16];
#pragma unroll
    for (int s = 0; s < 16; ++s) A[s] = -__expf(al[s]);
    float Dd = Dp[d];

    size_t hbase = (size_t)(b * kNC + c) * kDS * kDI + d;
    float h[16];
#pragma unroll
    for (int s = 0; s < 16; ++s) h[s] = h0v[hbase + s * kDI];

#pragma unroll 2
    for (int i = 0; i < kCH; ++i) {
        int p   = c * kCH + i;
        int t   = dir ? (kL - 1 - p) : p;
        int row = b * kL + t;
        float dt = bf2f(dtb[(size_t)row * kDI + d]);
        float xv = bf2f(xcb[(size_t)row * kDI + d]);
        float dx = dt * xv;
        const float4* bp = (const float4*)(dbl + (size_t)row * 64 + kR);
        float4 b0 = bp[0], b1 = bp[1], b2 = bp[2], b3 = bp[3];
        const float4* cp = (const float4*)(dbl + (size_t)row * 64 + kR + kDS);
        float4 c0 = cp[0], c1 = cp[1], c2 = cp[2], c3 = cp[3];
        float Bv[16] = {b0.x, b0.y, b0.z, b0.w, b1.x, b1.y, b1.z, b1.w,
                        b2.x, b2.y, b2.z, b2.w, b3.x, b3.y, b3.z, b3.w};
        float Cv[16] = {c0.x, c0.y, c0.z, c0.w, c1.x, c1.y, c1.z, c1.w,
                        c2.x, c2.y, c2.z, c2.w, c3.x, c3.y, c3.z, c3.w};
        float y = 0.f;
#pragma unroll
        for (int s = 0; s < 16; ++s) {
            float q = __expf(dt * A[s]);
            h[s] = fmaf(q, h[s], dx * Bv[s]);
            y = fmaf(h[s], Cv[s], y);
        }
        y += xv * Dd;
        float z = bf2f(zg[(size_t)row * 2048 + d]);
        yb[(size_t)row * kDI + d] = f2bf(y * silu_f(z));
    }
}

// ---------------------------------------------------------------------------
// LayerNorm over rows of 512 with optional 2 add-inputs and bf16 copy.
// ---------------------------------------------------------------------------
__global__ __launch_bounds__(128) void ln_k(
    const float* __restrict__ in, const float* __restrict__ a0,
    const float* __restrict__ a1,
    const float* __restrict__ g, const float* __restrict__ bb,
    float* __restrict__ out, unsigned short* __restrict__ outbf)
{
    int row = blockIdx.x;
    int tid = threadIdx.x;
    size_t off = (size_t)row * kDM + tid * 4;
    float4 v = *(const float4*)&in[off];
    if (a0) {
        float4 u = *(const float4*)&a0[off];
        float4 w = *(const float4*)&a1[off];
        v.x += u.x + w.x; v.y += u.y + w.y; v.z += u.z + w.z; v.w += u.w + w.w;
    }
    float s1 = v.x + v.y + v.z + v.w;
    float s2 = v.x * v.x + v.y * v.y + v.z * v.z + v.w * v.w;
#pragma unroll
    for (int o = 32; o >= 1; o >>= 1) {
        s1 += __shfl_xor(s1, o);
        s2 += __shfl_xor(s2, o);
    }
    __shared__ float red[4];
    if ((tid & 63) == 0) { red[(tid >> 6) * 2] = s1; red[(tid >> 6) * 2 + 1] = s2; }
    __syncthreads();
    s1 = red[0] + red[2];
    s2 = red[1] + red[3];
    float mu  = s1 * (1.f / kDM);
    float var = s2 * (1.f / kDM) - mu * mu;
    float rs  = rsqrtf(var + 1e-5f);
    int cn = tid * 4;
    float4 gv = *(const float4*)&g[cn];
    float4 bv = *(const float4*)&bb[cn];
    float4 o;
    o.x = (v.x - mu) * rs * gv.x + bv.x;
    o.y = (v.y - mu) * rs * gv.y + bv.y;
    o.z = (v.z - mu) * rs * gv.z + bv.z;
    o.w = (v.w - mu) * rs * gv.w + bv.w;
    *(float4*)&out[off] = o;
    if (outbf)
        *(uint2*)&outbf[off] = pack4(o);
}

// ---------------------------------------------------------------------------
extern "C" void kernel_launch(void* const* d_in, const int* in_sizes, int n_in,
                              void* d_out, int out_size, void* d_ws, size_t ws_size,
                              hipStream_t stream)
{
    const float* x_in    = (const float*)d_in[0];
    const float* in_w    = (const float*)d_in[1];
    const float* conv_w  = (const float*)d_in[2];
    const float* conv_b  = (const float*)d_in[3];
    const float* xproj_w = (const float*)d_in[4];
    const float* dt_w    = (const float*)d_in[5];
    const float* dt_b    = (const float*)d_in[6];
    const float* A_log   = (const float*)d_in[7];
    const float* Dp      = (const float*)d_in[8];
    const float* out_w   = (const float*)d_in[9];
    const float* ff_w1   = (const float*)d_in[10];
    const float* ff_b1   = (const float*)d_in[11];
    const float* ff_w2   = (const float*)d_in[12];
    const float* ff_b2   = (const float*)d_in[13];
    const float* ln1_g   = (const float*)d_in[14];
    const float* ln1_b   = (const float*)d_in[15];
    const float* ln2_g   = (const float*)d_in[16];
    const float* ln2_b   = (const float*)d_in[17];
    const float* lnf_g   = (const float*)d_in[18];
    const float* lnf_b   = (const float*)d_in[19];

    float* ws = (float*)d_ws;
    unsigned short* wsb = (unsigned short*)d_ws;

    // bf16 weights (bf16-elem offsets into wsb)
    unsigned short* wb_in  = wsb;                 // in_w   [0, 2097152)
    unsigned short* wb_xp  = wsb + 2097152;       // xproj  [.., 2228224)
    unsigned short* wb_out = wsb + 2228224;       // out_w  [.., 3276800)
    unsigned short* wb_f1  = wsb + 3276800;       // ff_w1  [.., 5373952)
    unsigned short* wb_f2  = wsb + 5373952;       // ff_w2  [.., 7471104)
    unsigned short* wb_dt  = wsb + 7471104;       // dt_w   [.., 7536640)

    constexpr size_t A0 = 3768320;                // f32-word offset of arena
    unsigned short* xbf  = (unsigned short*)(ws + A0);                  // 4.19M w
    unsigned short* xz2  = (unsigned short*)(ws + A0 + 4194304);        // 16.78M w
    unsigned short* xcb2 = (unsigned short*)(ws + A0 + 20971520);       // 8.39M w
    unsigned short* yb2  = (unsigned short*)(ws + A0 + 29360128);       // 8.39M w
    float*          Sb2  = ws + A0 + 37748736;                          // 8.39M w (S/h0)
    unsigned short* dtb2 = (unsigned short*)(ws + A0 + 46137344);       // 8.39M w
    float*          dbl2 = ws + A0 + 54525952;                          // 2.10M w
    unsigned short* dtin2= (unsigned short*)(ws + A0 + 56623104);       // 0.52M w
    float*          sdt2 = ws + A0 + 57147392;                          // 0.52M w
    // out-proj outputs alias scan scratch (dead after scan_emit)
    float*          o2   = ws + A0 + 37748736;                          // 16.78M w
    // FFN-phase aliases (mamba arena dead)
    float*          xn   = ws + A0;                                     // 8.39M w
    unsigned short* xnbf = (unsigned short*)(ws + A0 + 8388608);        // 4.19M w
    unsigned short* Hb   = (unsigned short*)(ws + A0 + 12582912);       // 16.78M w
    float*          t2   = ws + A0 + 29360128;                          // 8.39M w

    float* xcur = (float*)d_out;
    dim3 thr(256);

    WCvtArgs wa;
    wa.src[0] = in_w;    wa.end[0] = 2097152;
    wa.src[1] = xproj_w; wa.end[1] = 2228224;
    wa.src[2] = out_w;   wa.end[2] = 3276800;
    wa.src[3] = ff_w1;   wa.end[3] = 5373952;
    wa.src[4] = ff_w2;   wa.end[4] = 7471104;
    wa.src[5] = dt_w;    wa.end[5] = 7536640;
    cvt_weights_k<<<dim3(7536640 / 1024), thr, 0, stream>>>(wa, wsb);
    init_x_k<<<dim3(8192), thr, 0, stream>>>(x_in, xcur, xbf);

    for (int e = 0; e < 2; ++e) {
        // in-proj (both dirs fused): (kM x 512) @ (2048 x 512)^T -> xz2 bf16
        gemm8<256, 0, unsigned short><<<dim3(8, 64, 1), dim3(512), 0, stream>>>(
            xbf, 512, 0, wb_in + (size_t)e * 1048576, 0, xz2, 2048, 0,
            nullptr, 0, nullptr, 512);
        // conv + silu (both dirs, sliding window)
        conv_silu_k<<<dim3(512), dim3(128), 0, stream>>>(
            xz2, xcb2, conv_w + (size_t)e * 4096, conv_b + (size_t)e * 1024);
        // x-proj (both dirs): -> dbl f32 + dtin bf16
        gemm_bf16<5, 64, float><<<dim3(1, 128, 2), thr, 0, stream>>>(
            xcb2, 512, (size_t)kM * 512, wb_xp + (size_t)e * 65536, 32768,
            dbl2, 64, (size_t)kM * 64, nullptr, 0, dtin2, (size_t)kM * 32, 512);
        // dt-proj (both dirs): softplus -> dtb bf16
        gemm_bf16<1, 128, unsigned short><<<dim3(4, 128, 2), thr, 0, stream>>>(
            dtin2, 32, (size_t)kM * 32, wb_dt + (size_t)e * 32768, 16384,
            dtb2, 512, (size_t)kM * 512, dt_b + (size_t)e * 1024, 512,
            nullptr, 0, 32);
        // scans (both dirs)
        scan_chunk<<<dim3(kB * kNC * 2, 2), thr, 0, stream>>>(
            dtb2, xcb2, dbl2, A_log + (size_t)e * 16384, Sb2, sdt2);
        scan_carry<<<dim3(512, 2), thr, 0, stream>>>(
            Sb2, sdt2, A_log + (size_t)e * 16384);
        scan_emit<<<dim3(kB * kNC * 2, 2), thr, 0, stream>>>(
            dtb2, xcb2, dbl2, A_log + (size_t)e * 16384, Sb2,
            Dp + (size_t)e * 1024, xz2, yb2);
        // out-proj (both dirs) -> o2 (separate buffers; LN1 adds)
        gemm8<128, 0, float><<<dim3(2, 128, 2), dim3(512), 0, stream>>>(
            yb2, 512, (size_t)kM * 512, wb_out + (size_t)e * 524288, 262144,
            o2, 512, (size_t)kM * 512, nullptr, 0, nullptr, 512);
        // LN1: normalize (xcur + o0 + o1) -> xn f32 + xnbf bf16
        ln_k<<<dim3(kM), dim3(128), 0, stream>>>(
            xcur, o2, o2 + (size_t)kM * 512,
            ln1_g + e * kDM, ln1_b + e * kDM, xn, xnbf);
        // FFN1: gelu(xn @ w1^T + b1) -> Hb bf16
        gemm8<256, 3, unsigned short><<<dim3(8, 64, 1), dim3(512), 0, stream>>>(
            xnbf, 512, 0, wb_f1 + (size_t)e * 1048576, 0, Hb, 2048, 0,
            ff_b1 + (size_t)e * kDFF, 0, nullptr, 512);
        // FFN2: Hb @ w2^T + b2 + xn -> t2 f32
        gemm8<128, 4, float><<<dim3(2, 128, 1), dim3(512), 0, stream>>>(
            Hb, 2048, 0, wb_f2 + (size_t)e * 1048576, 0, t2, 512, 0,
            ff_b2 + (size_t)e * kDM, 0, xn, 2048);
        // LN2 -> xcur (+ bf16 snapshot for next layer)
        ln_k<<<dim3(kM), dim3(128), 0, stream>>>(
            t2, nullptr, nullptr, ln2_g + e * kDM, ln2_b + e * kDM, xcur,
            e == 0 ? xbf : nullptr);
    }
    ln_k<<<dim3(kM), dim3(128), 0, stream>>>(
        xcur, nullptr, nullptr, lnf_g, lnf_b, xcur, nullptr);
}